// Round 7
// baseline (275.545 us; speedup 1.0000x reference)
//
#include <hip/hip_runtime.h>
#include <stdint.h>

typedef unsigned short u16;
typedef __attribute__((ext_vector_type(8))) __bf16 bf16x8;
typedef __attribute__((ext_vector_type(4))) __bf16 bf16x4;
typedef __attribute__((ext_vector_type(4))) float f32x4;

#define QSCALE 0.1803368801111204f  /* 0.125 * log2(e): S in log2 domain */

#if __has_builtin(__builtin_amdgcn_exp2f)
#define EXP2(x) __builtin_amdgcn_exp2f(x)
#else
#define EXP2(x) exp2f(x)
#endif

__device__ __forceinline__ u16 f2bf(float f) {
  uint32_t u = __float_as_uint(f);
  u += 0x7fffu + ((u >> 16) & 1u);
  return (u16)(u >> 16);
}
__device__ __forceinline__ float bf2f(u16 h) {
  return __uint_as_float(((uint32_t)h) << 16);
}
__device__ __forceinline__ uint32_t pack2bf(float a, float b) {
  return (uint32_t)f2bf(a) | ((uint32_t)f2bf(b) << 16);
}

__device__ __forceinline__ void gl_lds16(const u16* g, u16* l) {
  __builtin_amdgcn_global_load_lds(
      (const __attribute__((address_space(1))) unsigned int*)g,
      (__attribute__((address_space(3))) unsigned int*)l, 16, 0, 0);
}

#define S_BAR() __builtin_amdgcn_s_barrier()
#define LGKM0() do { __asm__ volatile("s_waitcnt lgkmcnt(0)" ::: "memory"); \
                     __builtin_amdgcn_sched_barrier(0); } while (0)
#define VMC(N) do { __asm__ volatile("s_waitcnt vmcnt(" #N ")" ::: "memory"); \
                    __builtin_amdgcn_sched_barrier(0); } while (0)

// ---------------- dtype detector ----------------
__global__ void detect_dtype(const u16* __restrict__ x, int* __restrict__ flag) {
  __shared__ int any_huge;
  if (threadIdx.x == 0) any_huge = 0;
  __syncthreads();
  int huge = 0;
  for (int i = threadIdx.x; i < 4096; i += 256) {
    float v = bf2f(x[i]);
    if (!(fabsf(v) < 1e6f)) huge = 1;
  }
  if (huge) any_huge = 1;
  __syncthreads();
  if (threadIdx.x == 0) *flag = any_huge;  // 1 = inputs are fp32
}

// ---------------- fused prep (vectorized): weight transposes + x convert + biases ----
__global__ __launch_bounds__(256) void prep(
    const void* __restrict__ Wq, const void* __restrict__ Wk,
    const void* __restrict__ Wv, const void* __restrict__ Wo,
    const void* __restrict__ x,
    const void* __restrict__ bq, const void* __restrict__ bk,
    const void* __restrict__ bv, const void* __restrict__ bo,
    u16* __restrict__ WT, u16* __restrict__ WoT, u16* __restrict__ xb,
    float* __restrict__ biasf, const int* __restrict__ flag) {
  const int fl = *flag;
  int id = blockIdx.x;
  const int tid = threadIdx.x;
  if (id < 2560) {
    __shared__ u16 tile[64 * 72];
    const void* in; u16* outp; int N, rowoff;
    if (id < 1024)      { in = Wq; outp = WT;  N = 2048; rowoff = 0; }
    else if (id < 1280) { in = Wk; outp = WT;  N = 512;  rowoff = 2048; id -= 1024; }
    else if (id < 1536) { in = Wv; outp = WT;  N = 512;  rowoff = 2560; id -= 1280; }
    else                { in = Wo; outp = WoT; N = 2048; rowoff = 0;    id -= 1536; }
    int tiles_x = N >> 6;
    int nb = (id % tiles_x) * 64, kb = (id / tiles_x) * 64;
    const int kbase = (tid >> 4) * 4, nc = (tid & 15) * 4;
    if (fl) {
      float4 L[4];
#pragma unroll
      for (int p = 0; p < 4; ++p)
        L[p] = *(const float4*)&((const float*)in)[(size_t)(kb + kbase + p) * N + nb + nc];
#pragma unroll
      for (int nj = 0; nj < 4; ++nj) {
        uint2 w;
        w.x = pack2bf(((const float*)&L[0])[nj], ((const float*)&L[1])[nj]);
        w.y = pack2bf(((const float*)&L[2])[nj], ((const float*)&L[3])[nj]);
        *(uint2*)&tile[(nc + nj) * 72 + kbase] = w;
      }
    } else {
      uint2 L[4];
#pragma unroll
      for (int p = 0; p < 4; ++p)
        L[p] = *(const uint2*)&((const u16*)in)[(size_t)(kb + kbase + p) * N + nb + nc];
#pragma unroll
      for (int nj = 0; nj < 4; ++nj) {
        uint2 w;
        w.x = (uint32_t)((const u16*)&L[0])[nj] | ((uint32_t)((const u16*)&L[1])[nj] << 16);
        w.y = (uint32_t)((const u16*)&L[2])[nj] | ((uint32_t)((const u16*)&L[3])[nj] << 16);
        *(uint2*)&tile[(nc + nj) * 72 + kbase] = w;
      }
    }
    __syncthreads();
#pragma unroll
    for (int it = 0; it < 2; ++it) {
      int sid = it * 256 + tid;
      int row = sid >> 3, kseg = (sid & 7) * 8;
      uint4 v = *(const uint4*)&tile[row * 72 + kseg];
      *(uint4*)&outp[(size_t)(rowoff + nb + row) * 2048 + kb + kseg] = v;
    }
  } else if (id < 4608) {
    size_t base = ((size_t)(id - 2560) * 256 + tid) * 16;
    if (fl) {
      const float* xf = (const float*)x;
      float4 a = *(const float4*)&xf[base];
      float4 b = *(const float4*)&xf[base + 4];
      float4 c = *(const float4*)&xf[base + 8];
      float4 d = *(const float4*)&xf[base + 12];
      uint4 o0, o1;
      o0.x = pack2bf(a.x, a.y); o0.y = pack2bf(a.z, a.w);
      o0.z = pack2bf(b.x, b.y); o0.w = pack2bf(b.z, b.w);
      o1.x = pack2bf(c.x, c.y); o1.y = pack2bf(c.z, c.w);
      o1.z = pack2bf(d.x, d.y); o1.w = pack2bf(d.z, d.w);
      *(uint4*)&xb[base] = o0;
      *(uint4*)&xb[base + 8] = o1;
    } else {
      const u16* x16 = (const u16*)x;
      *(uint4*)&xb[base] = *(const uint4*)&x16[base];
      *(uint4*)&xb[base + 8] = *(const uint4*)&x16[base + 8];
    }
  } else {
    int i = (id - 4608) * 256 + tid;
    if (i < 5120) {
      const void* src; int idx;
      if (i < 2048)      { src = bq; idx = i; }
      else if (i < 2560) { src = bk; idx = i - 2048; }
      else if (i < 3072) { src = bv; idx = i - 2560; }
      else               { src = bo; idx = i - 3072; }
      biasf[i] = fl ? ((const float*)src)[idx] : bf2f(((const u16*)src)[idx]);
    }
  }
}

// =================== fused QKV projection: 128x384 tile, BK=64, 8 waves ===================
// (round-3 verified optimum: 59.4 us, MfmaUtil 35%, 0 bank conflicts)
__global__ __launch_bounds__(512, 2) void gemm_qkv(
    const u16* __restrict__ A, const u16* __restrict__ BT,
    const float* __restrict__ bias,
    u16* __restrict__ qo, u16* __restrict__ ko, u16* __restrict__ vo) {
  __shared__ __align__(16) u16 lds[65536];
  const int tid = threadIdx.x;
  const int wave = tid >> 6, lane = tid & 63;
  const int ln = lane & 15, quad = lane >> 4;
  const int sw8 = 8 * (quad ^ ((ln >> 1) & 3));
  const int m0 = blockIdx.y * 128, n0 = blockIdx.x * 384;

  u16* const A0b = lds;
  u16* const A1b = lds + 8192;
  u16* const B0b = lds + 16384;
  u16* const B1b = lds + 40960;

  const int srow = wave * 16 + (lane >> 2);
  const int skq = 8 * ((lane & 3) ^ ((lane >> 3) & 3));
  const u16* const sa = A + (size_t)(m0 + srow) * 2048 + skq;
  const u16* const sb = BT + (size_t)(n0 + srow) * 2048 + skq;
  const int dc8 = (wave * 64 + lane) * 8;

  auto stageA = [&](u16* dbase, int kt) {
    const u16* s = sa + kt;
    gl_lds16(s, dbase + dc8);
    gl_lds16(s + 32, dbase + dc8 + 4096);
  };
  auto stageB = [&](u16* dbase, int u, int kt) {
    const u16* s = sb + (size_t)u * 262144 + kt;
    u16* d = dbase + u * 4096 + dc8;
    gl_lds16(s, d);
    gl_lds16(s + 32, d + 12288);
  };

  f32x4 acc[8][3];
#pragma unroll
  for (int i = 0; i < 8; ++i)
#pragma unroll
    for (int j = 0; j < 3; ++j) acc[i][j] = {0.f, 0.f, 0.f, 0.f};

  bf16x8 aL[8], aH[8], b0f[2], b1f[2], b2f[2];
  auto rdAh = [&](bf16x8* dst, const u16* buf, int ibase) {
#pragma unroll
    for (int ii = 0; ii < 4; ++ii) {
      const int ro = ((ibase + ii) * 16 + ln) * 32 + sw8;
      dst[ii * 2 + 0] = *(const bf16x8*)&buf[ro];
      dst[ii * 2 + 1] = *(const bf16x8*)&buf[ro + 4096];
    }
  };
  auto rdBj = [&](bf16x8* dst, const u16* buf, int j) {
    const int ro = (wave * 48 + j * 16 + ln) * 32 + sw8;
    dst[0] = *(const bf16x8*)&buf[ro];
    dst[1] = *(const bf16x8*)&buf[ro + 12288];
  };
  auto mma8 = [&](const bf16x8* a4, const bf16x8* bj, int ibase, int j) {
#pragma unroll
    for (int ii = 0; ii < 4; ++ii)
#pragma unroll
      for (int kh = 0; kh < 2; ++kh)
        acc[ibase + ii][j] = __builtin_amdgcn_mfma_f32_16x16x32_bf16(
            bj[kh], a4[ii * 2 + kh], acc[ibase + ii][j], 0, 0, 0);
  };

  stageA(A0b, 0);
  stageB(B0b, 0, 0); stageB(B0b, 1, 0); stageB(B0b, 2, 0);
  stageA(A1b, 64);
  __asm__ volatile("s_waitcnt vmcnt(2)" ::: "memory");
  S_BAR();

#pragma unroll 1
  for (int it = 0; it < 16; ++it) {
    const int kk = it * 128;
#pragma unroll
    for (int h = 0; h < 2; ++h) {
      u16* const Ab = h ? A1b : A0b;
      u16* const Bb = h ? B1b : B0b;
      u16* const Bo = h ? B0b : B1b;
      const int kB = (kk + 64 + h * 64) & 2047;
      const int kA = (kk + 128 + h * 64) & 2047;
      rdAh(aL, Ab, 0); rdBj(b0f, Bb, 0);
      stageB(Bo, 0, kB);
      S_BAR(); LGKM0();
      __builtin_amdgcn_s_setprio(1); mma8(aL, b0f, 0, 0); __builtin_amdgcn_s_setprio(0);
      S_BAR();
      rdAh(aH, Ab, 4); rdBj(b1f, Bb, 1);
      stageB(Bo, 1, kB);
      S_BAR(); LGKM0();
      __builtin_amdgcn_s_setprio(1); mma8(aH, b0f, 4, 0); mma8(aL, b1f, 0, 1); __builtin_amdgcn_s_setprio(0);
      S_BAR();
      rdBj(b2f, Bb, 2);
      stageB(Bo, 2, kB);
      S_BAR(); LGKM0();
      __builtin_amdgcn_s_setprio(1); mma8(aH, b1f, 4, 1); mma8(aL, b2f, 0, 2); __builtin_amdgcn_s_setprio(0);
      S_BAR();
      stageA(Ab, kA);
      S_BAR();
      __builtin_amdgcn_s_setprio(1); mma8(aH, b2f, 4, 2); __builtin_amdgcn_s_setprio(0);
      VMC(2);
      S_BAR();
    }
  }

#pragma unroll
  for (int j = 0; j < 3; ++j) {
    const int gnf = n0 + wave * 48 + j * 16;
    const int gn = gnf + quad * 4;
    const float4 bsv = *(const float4*)&bias[gn];
    if (gnf < 2048) {
      const int hh = gn >> 6, dd = gn & 63;
#pragma unroll
      for (int i = 0; i < 8; ++i) {
        const int m = m0 + i * 16 + ln;
        const int b = m >> 10, s = m & 1023;
        uint2 st;
        st.x = pack2bf((acc[i][j][0] + bsv.x) * QSCALE, (acc[i][j][1] + bsv.y) * QSCALE);
        st.y = pack2bf((acc[i][j][2] + bsv.z) * QSCALE, (acc[i][j][3] + bsv.w) * QSCALE);
        *(uint2*)&qo[(((size_t)(b * 32 + hh)) * 1024 + s) * 64 + dd] = st;
      }
    } else if (gnf < 2560) {
      const int n2 = gn - 2048, hh = n2 >> 6, dd = n2 & 63;
#pragma unroll
      for (int i = 0; i < 8; ++i) {
        const int m = m0 + i * 16 + ln;
        const int b = m >> 10, s = m & 1023;
        uint2 st;
        st.x = pack2bf(acc[i][j][0] + bsv.x, acc[i][j][1] + bsv.y);
        st.y = pack2bf(acc[i][j][2] + bsv.z, acc[i][j][3] + bsv.w);
        *(uint2*)&ko[(((size_t)(b * 8 + hh)) * 1024 + s) * 64 + dd] = st;
      }
    } else {
      const int n2 = gn - 2560, hh = n2 >> 6, dd0 = n2 & 63;
#pragma unroll
      for (int i = 0; i < 8; ++i) {
        const int m = m0 + i * 16 + ln;
        const int b = m >> 10, s = m & 1023;
        const size_t vb = ((size_t)(b * 8 + hh) * 64 + dd0) * 1024 + s;
        vo[vb]        = f2bf(acc[i][j][0] + bsv.x);
        vo[vb + 1024] = f2bf(acc[i][j][1] + bsv.y);
        vo[vb + 2048] = f2bf(acc[i][j][2] + bsv.z);
        vo[vb + 3072] = f2bf(acc[i][j][3] + bsv.w);
      }
    }
  }
}

// =================== O projection: 256x128 tile, BK=64, 8 waves ===================
// (round-3 verified code)
__global__ __launch_bounds__(512, 2) void gemm_o(
    const u16* __restrict__ A, const u16* __restrict__ BT,
    const float* __restrict__ bias, u16* __restrict__ o0,
    const int* __restrict__ flag) {
  __shared__ __align__(16) u16 lds[49152];
  const int tid = threadIdx.x;
  const int wave = tid >> 6, lane = tid & 63;
  const int ln = lane & 15, quad = lane >> 4;
  const int sw8 = 8 * (quad ^ ((ln >> 1) & 3));
  const int wm = (wave >> 2) * 128, wn = (wave & 3) * 32;
  const int m0 = blockIdx.y * 256, n0 = blockIdx.x * 128;
  const int fl = *flag;

  u16* const A0b = lds;
  u16* const A1b = lds + 16384;
  u16* const B0b = lds + 32768;
  u16* const B1b = lds + 40960;

  const int srow = wave * 16 + (lane >> 2);
  const int skq = 8 * ((lane & 3) ^ ((lane >> 3) & 3));
  const u16* const sa = A + (size_t)(m0 + srow) * 2048 + skq;
  const u16* const sb = BT + (size_t)(n0 + srow) * 2048 + skq;
  const int dc8 = (wave * 64 + lane) * 8;

  auto stageA = [&](u16* dbase, int H, int kt) {
    const u16* s = sa + (size_t)H * 262144 + kt;
    u16* d = dbase + H * 4096 + dc8;
    gl_lds16(s, d);
    gl_lds16(s + 32, d + 8192);
  };
  auto stageB = [&](u16* dbase, int kt) {
    const u16* s = sb + kt;
    gl_lds16(s, dbase + dc8);
    gl_lds16(s + 32, dbase + dc8 + 4096);
  };

  f32x4 acc[8][2];
#pragma unroll
  for (int i = 0; i < 8; ++i)
#pragma unroll
    for (int j = 0; j < 2; ++j) acc[i][j] = {0.f, 0.f, 0.f, 0.f};

  bf16x8 aL[8], aH[8], b0f[2], b1f[2];
  auto rdAh = [&](bf16x8* dst, const u16* buf, int ibase) {
#pragma unroll
    for (int ii = 0; ii < 4; ++ii) {
      const int ro = (wm + (ibase + ii) * 16 + ln) * 32 + sw8;
      dst[ii * 2 + 0] = *(const bf16x8*)&buf[ro];
      dst[ii * 2 + 1] = *(const bf16x8*)&buf[ro + 8192];
    }
  };
  auto rdBj = [&](bf16x8* dst, const u16* buf, int j) {
    const int ro = (wn + j * 16 + ln) * 32 + sw8;
    dst[0] = *(const bf16x8*)&buf[ro];
    dst[1] = *(const bf16x8*)&buf[ro + 4096];
  };
  auto mma8 = [&](const bf16x8* a4, const bf16x8* bj, int ibase, int j) {
#pragma unroll
    for (int ii = 0; ii < 4; ++ii)
#pragma unroll
      for (int kh = 0; kh < 2; ++kh)
        acc[ibase + ii][j] = __builtin_amdgcn_mfma_f32_16x16x32_bf16(
            bj[kh], a4[ii * 2 + kh], acc[ibase + ii][j], 0, 0, 0);
  };

  stageA(A0b, 0, 0); stageA(A0b, 1, 0);
  stageB(B0b, 0);
  stageA(A1b, 0, 64); stageA(A1b, 1, 64);
  __asm__ volatile("s_waitcnt vmcnt(4)" ::: "memory");
  S_BAR();

#pragma unroll 1
  for (int it = 0; it < 16; ++it) {
    const int kk = it * 128;
#pragma unroll
    for (int h = 0; h < 2; ++h) {
      u16* const Ab = h ? A1b : A0b;
      u16* const Bb = h ? B1b : B0b;
      u16* const Bo = h ? B0b : B1b;
      const int kB = (kk + 64 + h * 64) & 2047;
      const int kA = (kk + 128 + h * 64) & 2047;
      rdAh(aL, Ab, 0); rdBj(b0f, Bb, 0);
      stageB(Bo, kB);
      S_BAR(); LGKM0();
      __builtin_amdgcn_s_setprio(1); mma8(aL, b0f, 0, 0); __builtin_amdgcn_s_setprio(0);
      S_BAR();
      rdAh(aH, Ab, 4); rdBj(b1f, Bb, 1);
      S_BAR(); LGKM0();
      __builtin_amdgcn_s_setprio(1); mma8(aH, b0f, 4, 0); __builtin_amdgcn_s_setprio(0);
      S_BAR();
      stageA(Ab, 0, kA);
      S_BAR();
      __builtin_amdgcn_s_setprio(1); mma8(aH, b1f, 4, 1); __builtin_amdgcn_s_setprio(0);
      S_BAR();
      stageA(Ab, 1, kA);
      S_BAR();
      __builtin_amdgcn_s_setprio(1); mma8(aL, b1f, 0, 1); __builtin_amdgcn_s_setprio(0);
      VMC(4);
      S_BAR();
    }
  }

#pragma unroll
  for (int j = 0; j < 2; ++j) {
    const int nbase = n0 + wn + j * 16 + quad * 4;
    const float4 bsv = *(const float4*)&bias[nbase];
#pragma unroll
    for (int i = 0; i < 8; ++i) {
      const int m = m0 + wm + i * 16 + ln;
      float v0 = acc[i][j][0] + bsv.x, v1 = acc[i][j][1] + bsv.y;
      float v2 = acc[i][j][2] + bsv.z, v3 = acc[i][j][3] + bsv.w;
      if (fl) {
        float4 st = {v0, v1, v2, v3};
        *(float4*)&((float*)o0)[(size_t)m * 2048 + nbase] = st;
      } else {
        uint2 st; st.x = pack2bf(v0, v1); st.y = pack2bf(v2, v3);
        *(uint2*)&o0[(size_t)m * 2048 + nbase] = st;
      }
    }
  }
}

// ---------------- flash attention, transposed-S formulation (proven R3 code) ----------------
// Single change vs R3: Pl stride 68 -> 72. Stride-68 put all Pl traffic on even banks
// (addr/4 = ln*34+... == 2*ln mod 32) -> the measured 8.4M SQ_LDS_BANK_CONFLICT.
// Stride 72 (addr/4 = ln*36 == 4*ln mod 32) gives conflict-free writes (16 bank-pairs
// x 4 lanes) and reads (8 groups x 8 lanes), matching the already-clean Kl/Vl layout.
__global__ __launch_bounds__(256) void attn_kernel(
    const u16* __restrict__ q_ws, const u16* __restrict__ k_ws,
    const u16* __restrict__ vt_ws, u16* __restrict__ ctx) {
  __shared__ u16 Kl[64 * 72];
  __shared__ u16 Vl[64 * 72];
  __shared__ u16 Pl[4 * 16 * 72];
  const int tid = threadIdx.x;
  const int wave = tid >> 6, lane = tid & 63;
  const int ln = lane & 15, quad = lane >> 4;
  const int qt = blockIdx.x;
  const int bh = blockIdx.y;
  const int b = bh >> 5, h = bh & 31, kvh = h >> 2;
  const int q0 = qt * 64;
  const size_t qbase = (size_t)bh * 1024 * 64;
  const u16* kptr = k_ws + (size_t)(b * 8 + kvh) * 1024 * 64;
  const u16* vptr = vt_ws + (size_t)(b * 8 + kvh) * 64 * 1024;

  const int qrow = q0 + wave * 16 + ln;
  bf16x8 qf0 = *(const bf16x8*)&q_ws[qbase + (size_t)qrow * 64 + quad * 8];
  bf16x8 qf1 = *(const bf16x8*)&q_ws[qbase + (size_t)qrow * 64 + 32 + quad * 8];

  float lsum = 0.f;
  f32x4 oacc[4];
#pragma unroll
  for (int t = 0; t < 4; ++t) oacc[t] = {0.f, 0.f, 0.f, 0.f};

  const int kr0 = tid >> 3, kp0 = (tid & 7) * 8;
  const int kr1 = kr0 + 32;
  const int prow = wave * 16 * 72 + ln * 72;

  uint4 kv0 = *(const uint4*)&kptr[(size_t)kr0 * 64 + kp0];
  uint4 kv1 = *(const uint4*)&kptr[(size_t)kr1 * 64 + kp0];
  uint4 vv0 = *(const uint4*)&vptr[(size_t)kr0 * 1024 + kp0];
  uint4 vv1 = *(const uint4*)&vptr[(size_t)kr1 * 1024 + kp0];

  for (int kb = 0; kb < 1024; kb += 64) {
    __syncthreads();
    *(uint4*)&Kl[kr0 * 72 + kp0] = kv0;
    *(uint4*)&Kl[kr1 * 72 + kp0] = kv1;
    *(uint4*)&Vl[kr0 * 72 + kp0] = vv0;
    *(uint4*)&Vl[kr1 * 72 + kp0] = vv1;
    __syncthreads();

    {
      int nkb = (kb + 64) & 1023;
      kv0 = *(const uint4*)&kptr[(size_t)(nkb + kr0) * 64 + kp0];
      kv1 = *(const uint4*)&kptr[(size_t)(nkb + kr1) * 64 + kp0];
      vv0 = *(const uint4*)&vptr[(size_t)kr0 * 1024 + nkb + kp0];
      vv1 = *(const uint4*)&vptr[(size_t)kr1 * 1024 + nkb + kp0];
    }

    f32x4 sacc[4];
#pragma unroll
    for (int t = 0; t < 4; ++t) sacc[t] = {0.f, 0.f, 0.f, 0.f};
#pragma unroll
    for (int t = 0; t < 4; ++t) {
      bf16x8 kf0 = *(const bf16x8*)&Kl[(t * 16 + ln) * 72 + quad * 8];
      bf16x8 kf1 = *(const bf16x8*)&Kl[(t * 16 + ln) * 72 + 32 + quad * 8];
      sacc[t] = __builtin_amdgcn_mfma_f32_16x16x32_bf16(kf0, qf0, sacc[t], 0, 0, 0);
      sacc[t] = __builtin_amdgcn_mfma_f32_16x16x32_bf16(kf1, qf1, sacc[t], 0, 0, 0);
    }

    uint2 pk[4];
#pragma unroll
    for (int t = 0; t < 4; ++t) {
      float p0 = EXP2(sacc[t][0]);
      float p1 = EXP2(sacc[t][1]);
      float p2 = EXP2(sacc[t][2]);
      float p3 = EXP2(sacc[t][3]);
      lsum += (p0 + p1) + (p2 + p3);
      pk[t].x = __builtin_amdgcn_perm(__float_as_uint(p1), __float_as_uint(p0), 0x07060302u);
      pk[t].y = __builtin_amdgcn_perm(__float_as_uint(p3), __float_as_uint(p2), 0x07060302u);
    }
#pragma unroll
    for (int t = 0; t < 4; ++t)
      *(uint2*)&Pl[prow + t * 16 + quad * 4] = pk[t];
    __asm__ volatile("s_waitcnt lgkmcnt(0)" ::: "memory");

    bf16x8 pf0 = *(const bf16x8*)&Pl[prow + quad * 8];
    bf16x8 pf1 = *(const bf16x8*)&Pl[prow + 32 + quad * 8];

#pragma unroll
    for (int t = 0; t < 4; ++t) {
      bf16x8 vf0 = *(const bf16x8*)&Vl[(t * 16 + ln) * 72 + quad * 8];
      bf16x8 vf1 = *(const bf16x8*)&Vl[(t * 16 + ln) * 72 + 32 + quad * 8];
      oacc[t] = __builtin_amdgcn_mfma_f32_16x16x32_bf16(vf0, pf0, oacc[t], 0, 0, 0);
      oacc[t] = __builtin_amdgcn_mfma_f32_16x16x32_bf16(vf1, pf1, oacc[t], 0, 0, 0);
    }
  }

  float l2 = lsum + __shfl_xor(lsum, 16);
  l2 += __shfl_xor(l2, 32);
  const float inv = 1.0f / l2;

  const size_t obase = (size_t)(b * 1024 + qrow) * 2048 + h * 64;
#pragma unroll
  for (int t = 0; t < 4; ++t) {
    uint2 st;
    st.x = pack2bf(oacc[t][0] * inv, oacc[t][1] * inv);
    st.y = pack2bf(oacc[t][2] * inv, oacc[t][3] * inv);
    *(uint2*)&ctx[obase + t * 16 + quad * 4] = st;
  }
}

extern "C" void kernel_launch(void* const* d_in, const int* in_sizes, int n_in,
                              void* d_out, int out_size, void* d_ws, size_t ws_size,
                              hipStream_t stream) {
  const void* x  = d_in[0];
  const void* Wq = d_in[1];
  const void* bq = d_in[2];
  const void* Wk = d_in[3];
  const void* bk = d_in[4];
  const void* Wv = d_in[5];
  const void* bv = d_in[6];
  const void* Wo = d_in[7];
  const void* bo = d_in[8];
  char* ws = (char*)d_ws;

  u16* WT    = (u16*)(ws + 0);          // [3072][2048] bf16 (WqT|WkT|WvT)
  u16* WoT   = (u16*)(ws + 12582912);   // [2048][2048]
  u16* q_ws  = (u16*)(ws + 20971520);   // [4,32,1024,64]
  u16* k_ws  = (u16*)(ws + 37748736);   // [4,8,1024,64]
  u16* vt_ws = (u16*)(ws + 41943040);   // [4,8,64,1024]
  u16* c_ws  = (u16*)(ws + 46137344);   // [4096][2048]
  u16* xb    = (u16*)(ws + 62914560);   // [4096][2048] bf16 x
  float* biasf = (float*)(ws + 79691776); // 5120 fp32 packed biases
  int* flag  = (int*)(ws + 79712256);

  detect_dtype<<<1, 256, 0, stream>>>((const u16*)x, flag);
  prep<<<4628, 256, 0, stream>>>(Wq, Wk, Wv, Wo, x, bq, bk, bv, bo,
                                 WT, WoT, xb, biasf, flag);

  gemm_qkv<<<dim3(8, 32), 512, 0, stream>>>(xb, WT, biasf, q_ws, k_ws, vt_ws);
  attn_kernel<<<dim3(16, 128), 256, 0, stream>>>(q_ws, k_ws, vt_ws, c_ws);
  gemm_o<<<dim3(16, 16), 512, 0, stream>>>(c_ws, WoT, biasf + 3072, (u16*)d_out, flag);
}

// Round 8
// 263.732 us; speedup vs baseline: 1.0448x; 1.0448x over previous
//
#include <hip/hip_runtime.h>
#include <stdint.h>

typedef unsigned short u16;
typedef __attribute__((ext_vector_type(8))) __bf16 bf16x8;
typedef __attribute__((ext_vector_type(4))) __bf16 bf16x4;
typedef __attribute__((ext_vector_type(4))) float f32x4;
typedef __attribute__((ext_vector_type(16))) float f32x16;

#define QSCALE 0.1803368801111204f  /* 0.125 * log2(e): S in log2 domain */

#if __has_builtin(__builtin_amdgcn_exp2f)
#define EXP2(x) __builtin_amdgcn_exp2f(x)
#else
#define EXP2(x) exp2f(x)
#endif

__device__ __forceinline__ u16 f2bf(float f) {
  uint32_t u = __float_as_uint(f);
  u += 0x7fffu + ((u >> 16) & 1u);
  return (u16)(u >> 16);
}
__device__ __forceinline__ float bf2f(u16 h) {
  return __uint_as_float(((uint32_t)h) << 16);
}
__device__ __forceinline__ uint32_t pack2bf(float a, float b) {
  return (uint32_t)f2bf(a) | ((uint32_t)f2bf(b) << 16);
}

__device__ __forceinline__ void gl_lds16(const u16* g, u16* l) {
  __builtin_amdgcn_global_load_lds(
      (const __attribute__((address_space(1))) unsigned int*)g,
      (__attribute__((address_space(3))) unsigned int*)l, 16, 0, 0);
}

__device__ __forceinline__ uint32_t cvt_pk_bf16(float lo, float hi) {
  uint32_t r;
  asm("v_cvt_pk_bf16_f32 %0, %1, %2" : "=v"(r) : "v"(lo), "v"(hi));
  return r;
}
// v_permlane32_swap_b32: x' = {x.lo, y.lo}, y' = {x.hi, y.hi} (lo/hi = lanes 0-31/32-63)
__device__ __forceinline__ void pl32_swap(uint32_t& x, uint32_t& y) {
  asm("v_permlane32_swap_b32 %0, %1" : "+v"(x), "+v"(y));
}

#define S_BAR() __builtin_amdgcn_s_barrier()
#define LGKM0() do { __asm__ volatile("s_waitcnt lgkmcnt(0)" ::: "memory"); \
                     __builtin_amdgcn_sched_barrier(0); } while (0)
#define VMC(N) do { __asm__ volatile("s_waitcnt vmcnt(" #N ")" ::: "memory"); \
                    __builtin_amdgcn_sched_barrier(0); } while (0)

// ---------------- fused prep: self-computed dtype flag + weight transposes + x + biases ----
// detect_dtype fused in: each block derives fl from x's first 8 KB (L2-hot after block 0);
// block 0 publishes it for gemm_o (same-stream kernel-boundary visibility).
__global__ __launch_bounds__(256) void prep(
    const void* __restrict__ Wq, const void* __restrict__ Wk,
    const void* __restrict__ Wv, const void* __restrict__ Wo,
    const void* __restrict__ x,
    const void* __restrict__ bq, const void* __restrict__ bk,
    const void* __restrict__ bv, const void* __restrict__ bo,
    u16* __restrict__ WT, u16* __restrict__ WoT, u16* __restrict__ xb,
    float* __restrict__ biasf, int* __restrict__ flagp) {
  int id = blockIdx.x;
  const int tid = threadIdx.x;

  __shared__ int sfl;
  if (tid == 0) sfl = 0;
  int huge = 0;
  for (int i = tid; i < 4096; i += 256) {
    float v = bf2f(((const u16*)x)[i]);
    if (!(fabsf(v) < 1e6f)) huge = 1;
  }
  __syncthreads();
  if (huge) sfl = 1;
  __syncthreads();
  const int fl = sfl;  // 1 = inputs are fp32
  if (id == 0 && tid == 0) *flagp = fl;

  if (id < 2560) {
    __shared__ u16 tile[64 * 72];
    const void* in; u16* outp; int N, rowoff;
    if (id < 1024)      { in = Wq; outp = WT;  N = 2048; rowoff = 0; }
    else if (id < 1280) { in = Wk; outp = WT;  N = 512;  rowoff = 2048; id -= 1024; }
    else if (id < 1536) { in = Wv; outp = WT;  N = 512;  rowoff = 2560; id -= 1280; }
    else                { in = Wo; outp = WoT; N = 2048; rowoff = 0;    id -= 1536; }
    int tiles_x = N >> 6;
    int nb = (id % tiles_x) * 64, kb = (id / tiles_x) * 64;
    const int kbase = (tid >> 4) * 4, nc = (tid & 15) * 4;
    if (fl) {
      float4 L[4];
#pragma unroll
      for (int p = 0; p < 4; ++p)
        L[p] = *(const float4*)&((const float*)in)[(size_t)(kb + kbase + p) * N + nb + nc];
#pragma unroll
      for (int nj = 0; nj < 4; ++nj) {
        uint2 w;
        w.x = pack2bf(((const float*)&L[0])[nj], ((const float*)&L[1])[nj]);
        w.y = pack2bf(((const float*)&L[2])[nj], ((const float*)&L[3])[nj]);
        *(uint2*)&tile[(nc + nj) * 72 + kbase] = w;
      }
    } else {
      uint2 L[4];
#pragma unroll
      for (int p = 0; p < 4; ++p)
        L[p] = *(const uint2*)&((const u16*)in)[(size_t)(kb + kbase + p) * N + nb + nc];
#pragma unroll
      for (int nj = 0; nj < 4; ++nj) {
        uint2 w;
        w.x = (uint32_t)((const u16*)&L[0])[nj] | ((uint32_t)((const u16*)&L[1])[nj] << 16);
        w.y = (uint32_t)((const u16*)&L[2])[nj] | ((uint32_t)((const u16*)&L[3])[nj] << 16);
        *(uint2*)&tile[(nc + nj) * 72 + kbase] = w;
      }
    }
    __syncthreads();
#pragma unroll
    for (int it = 0; it < 2; ++it) {
      int sid = it * 256 + tid;
      int row = sid >> 3, kseg = (sid & 7) * 8;
      uint4 v = *(const uint4*)&tile[row * 72 + kseg];
      *(uint4*)&outp[(size_t)(rowoff + nb + row) * 2048 + kb + kseg] = v;
    }
  } else if (id < 4608) {
    size_t base = ((size_t)(id - 2560) * 256 + tid) * 16;
    if (fl) {
      const float* xf = (const float*)x;
      float4 a = *(const float4*)&xf[base];
      float4 b = *(const float4*)&xf[base + 4];
      float4 c = *(const float4*)&xf[base + 8];
      float4 d = *(const float4*)&xf[base + 12];
      uint4 o0, o1;
      o0.x = pack2bf(a.x, a.y); o0.y = pack2bf(a.z, a.w);
      o0.z = pack2bf(b.x, b.y); o0.w = pack2bf(b.z, b.w);
      o1.x = pack2bf(c.x, c.y); o1.y = pack2bf(c.z, c.w);
      o1.z = pack2bf(d.x, d.y); o1.w = pack2bf(d.z, d.w);
      *(uint4*)&xb[base] = o0;
      *(uint4*)&xb[base + 8] = o1;
    } else {
      const u16* x16 = (const u16*)x;
      *(uint4*)&xb[base] = *(const uint4*)&x16[base];
      *(uint4*)&xb[base + 8] = *(const uint4*)&x16[base + 8];
    }
  } else {
    int i = (id - 4608) * 256 + tid;
    if (i < 5120) {
      const void* src; int idx;
      if (i < 2048)      { src = bq; idx = i; }
      else if (i < 2560) { src = bk; idx = i - 2048; }
      else if (i < 3072) { src = bv; idx = i - 2560; }
      else               { src = bo; idx = i - 3072; }
      biasf[i] = fl ? ((const float*)src)[idx] : bf2f(((const u16*)src)[idx]);
    }
  }
}

// =================== fused QKV projection: 128x384 tile, BK=64, 8 waves ===================
// (round-3 verified optimum: 59.4 us, MfmaUtil 35%, 0 bank conflicts)
__global__ __launch_bounds__(512, 2) void gemm_qkv(
    const u16* __restrict__ A, const u16* __restrict__ BT,
    const float* __restrict__ bias,
    u16* __restrict__ qo, u16* __restrict__ ko, u16* __restrict__ vo) {
  __shared__ __align__(16) u16 lds[65536];
  const int tid = threadIdx.x;
  const int wave = tid >> 6, lane = tid & 63;
  const int ln = lane & 15, quad = lane >> 4;
  const int sw8 = 8 * (quad ^ ((ln >> 1) & 3));
  const int m0 = blockIdx.y * 128, n0 = blockIdx.x * 384;

  u16* const A0b = lds;
  u16* const A1b = lds + 8192;
  u16* const B0b = lds + 16384;
  u16* const B1b = lds + 40960;

  const int srow = wave * 16 + (lane >> 2);
  const int skq = 8 * ((lane & 3) ^ ((lane >> 3) & 3));
  const u16* const sa = A + (size_t)(m0 + srow) * 2048 + skq;
  const u16* const sb = BT + (size_t)(n0 + srow) * 2048 + skq;
  const int dc8 = (wave * 64 + lane) * 8;

  auto stageA = [&](u16* dbase, int kt) {
    const u16* s = sa + kt;
    gl_lds16(s, dbase + dc8);
    gl_lds16(s + 32, dbase + dc8 + 4096);
  };
  auto stageB = [&](u16* dbase, int u, int kt) {
    const u16* s = sb + (size_t)u * 262144 + kt;
    u16* d = dbase + u * 4096 + dc8;
    gl_lds16(s, d);
    gl_lds16(s + 32, d + 12288);
  };

  f32x4 acc[8][3];
#pragma unroll
  for (int i = 0; i < 8; ++i)
#pragma unroll
    for (int j = 0; j < 3; ++j) acc[i][j] = {0.f, 0.f, 0.f, 0.f};

  bf16x8 aL[8], aH[8], b0f[2], b1f[2], b2f[2];
  auto rdAh = [&](bf16x8* dst, const u16* buf, int ibase) {
#pragma unroll
    for (int ii = 0; ii < 4; ++ii) {
      const int ro = ((ibase + ii) * 16 + ln) * 32 + sw8;
      dst[ii * 2 + 0] = *(const bf16x8*)&buf[ro];
      dst[ii * 2 + 1] = *(const bf16x8*)&buf[ro + 4096];
    }
  };
  auto rdBj = [&](bf16x8* dst, const u16* buf, int j) {
    const int ro = (wave * 48 + j * 16 + ln) * 32 + sw8;
    dst[0] = *(const bf16x8*)&buf[ro];
    dst[1] = *(const bf16x8*)&buf[ro + 12288];
  };
  auto mma8 = [&](const bf16x8* a4, const bf16x8* bj, int ibase, int j) {
#pragma unroll
    for (int ii = 0; ii < 4; ++ii)
#pragma unroll
      for (int kh = 0; kh < 2; ++kh)
        acc[ibase + ii][j] = __builtin_amdgcn_mfma_f32_16x16x32_bf16(
            bj[kh], a4[ii * 2 + kh], acc[ibase + ii][j], 0, 0, 0);
  };

  stageA(A0b, 0);
  stageB(B0b, 0, 0); stageB(B0b, 1, 0); stageB(B0b, 2, 0);
  stageA(A1b, 64);
  __asm__ volatile("s_waitcnt vmcnt(2)" ::: "memory");
  S_BAR();

#pragma unroll 1
  for (int it = 0; it < 16; ++it) {
    const int kk = it * 128;
#pragma unroll
    for (int h = 0; h < 2; ++h) {
      u16* const Ab = h ? A1b : A0b;
      u16* const Bb = h ? B1b : B0b;
      u16* const Bo = h ? B0b : B1b;
      const int kB = (kk + 64 + h * 64) & 2047;
      const int kA = (kk + 128 + h * 64) & 2047;
      rdAh(aL, Ab, 0); rdBj(b0f, Bb, 0);
      stageB(Bo, 0, kB);
      S_BAR(); LGKM0();
      __builtin_amdgcn_s_setprio(1); mma8(aL, b0f, 0, 0); __builtin_amdgcn_s_setprio(0);
      S_BAR();
      rdAh(aH, Ab, 4); rdBj(b1f, Bb, 1);
      stageB(Bo, 1, kB);
      S_BAR(); LGKM0();
      __builtin_amdgcn_s_setprio(1); mma8(aH, b0f, 4, 0); mma8(aL, b1f, 0, 1); __builtin_amdgcn_s_setprio(0);
      S_BAR();
      rdBj(b2f, Bb, 2);
      stageB(Bo, 2, kB);
      S_BAR(); LGKM0();
      __builtin_amdgcn_s_setprio(1); mma8(aH, b1f, 4, 1); mma8(aL, b2f, 0, 2); __builtin_amdgcn_s_setprio(0);
      S_BAR();
      stageA(Ab, kA);
      S_BAR();
      __builtin_amdgcn_s_setprio(1); mma8(aH, b2f, 4, 2); __builtin_amdgcn_s_setprio(0);
      VMC(2);
      S_BAR();
    }
  }

#pragma unroll
  for (int j = 0; j < 3; ++j) {
    const int gnf = n0 + wave * 48 + j * 16;
    const int gn = gnf + quad * 4;
    const float4 bsv = *(const float4*)&bias[gn];
    if (gnf < 2048) {
      const int hh = gn >> 6, dd = gn & 63;
#pragma unroll
      for (int i = 0; i < 8; ++i) {
        const int m = m0 + i * 16 + ln;
        const int b = m >> 10, s = m & 1023;
        uint2 st;
        st.x = pack2bf((acc[i][j][0] + bsv.x) * QSCALE, (acc[i][j][1] + bsv.y) * QSCALE);
        st.y = pack2bf((acc[i][j][2] + bsv.z) * QSCALE, (acc[i][j][3] + bsv.w) * QSCALE);
        *(uint2*)&qo[(((size_t)(b * 32 + hh)) * 1024 + s) * 64 + dd] = st;
      }
    } else if (gnf < 2560) {
      const int n2 = gn - 2048, hh = n2 >> 6, dd = n2 & 63;
#pragma unroll
      for (int i = 0; i < 8; ++i) {
        const int m = m0 + i * 16 + ln;
        const int b = m >> 10, s = m & 1023;
        uint2 st;
        st.x = pack2bf(acc[i][j][0] + bsv.x, acc[i][j][1] + bsv.y);
        st.y = pack2bf(acc[i][j][2] + bsv.z, acc[i][j][3] + bsv.w);
        *(uint2*)&ko[(((size_t)(b * 8 + hh)) * 1024 + s) * 64 + dd] = st;
      }
    } else {
      const int n2 = gn - 2560, hh = n2 >> 6, dd0 = n2 & 63;
#pragma unroll
      for (int i = 0; i < 8; ++i) {
        const int m = m0 + i * 16 + ln;
        const int b = m >> 10, s = m & 1023;
        const size_t vb = ((size_t)(b * 8 + hh) * 64 + dd0) * 1024 + s;
        vo[vb]        = f2bf(acc[i][j][0] + bsv.x);
        vo[vb + 1024] = f2bf(acc[i][j][1] + bsv.y);
        vo[vb + 2048] = f2bf(acc[i][j][2] + bsv.z);
        vo[vb + 3072] = f2bf(acc[i][j][3] + bsv.w);
      }
    }
  }
}

// =================== O projection: 256x128 tile, BK=64, 8 waves ===================
// (round-3 verified code)
__global__ __launch_bounds__(512, 2) void gemm_o(
    const u16* __restrict__ A, const u16* __restrict__ BT,
    const float* __restrict__ bias, u16* __restrict__ o0,
    const int* __restrict__ flag) {
  __shared__ __align__(16) u16 lds[49152];
  const int tid = threadIdx.x;
  const int wave = tid >> 6, lane = tid & 63;
  const int ln = lane & 15, quad = lane >> 4;
  const int sw8 = 8 * (quad ^ ((ln >> 1) & 3));
  const int wm = (wave >> 2) * 128, wn = (wave & 3) * 32;
  const int m0 = blockIdx.y * 256, n0 = blockIdx.x * 128;
  const int fl = *flag;

  u16* const A0b = lds;
  u16* const A1b = lds + 16384;
  u16* const B0b = lds + 32768;
  u16* const B1b = lds + 40960;

  const int srow = wave * 16 + (lane >> 2);
  const int skq = 8 * ((lane & 3) ^ ((lane >> 3) & 3));
  const u16* const sa = A + (size_t)(m0 + srow) * 2048 + skq;
  const u16* const sb = BT + (size_t)(n0 + srow) * 2048 + skq;
  const int dc8 = (wave * 64 + lane) * 8;

  auto stageA = [&](u16* dbase, int H, int kt) {
    const u16* s = sa + (size_t)H * 262144 + kt;
    u16* d = dbase + H * 4096 + dc8;
    gl_lds16(s, d);
    gl_lds16(s + 32, d + 8192);
  };
  auto stageB = [&](u16* dbase, int kt) {
    const u16* s = sb + kt;
    gl_lds16(s, dbase + dc8);
    gl_lds16(s + 32, dbase + dc8 + 4096);
  };

  f32x4 acc[8][2];
#pragma unroll
  for (int i = 0; i < 8; ++i)
#pragma unroll
    for (int j = 0; j < 2; ++j) acc[i][j] = {0.f, 0.f, 0.f, 0.f};

  bf16x8 aL[8], aH[8], b0f[2], b1f[2];
  auto rdAh = [&](bf16x8* dst, const u16* buf, int ibase) {
#pragma unroll
    for (int ii = 0; ii < 4; ++ii) {
      const int ro = (wm + (ibase + ii) * 16 + ln) * 32 + sw8;
      dst[ii * 2 + 0] = *(const bf16x8*)&buf[ro];
      dst[ii * 2 + 1] = *(const bf16x8*)&buf[ro + 8192];
    }
  };
  auto rdBj = [&](bf16x8* dst, const u16* buf, int j) {
    const int ro = (wn + j * 16 + ln) * 32 + sw8;
    dst[0] = *(const bf16x8*)&buf[ro];
    dst[1] = *(const bf16x8*)&buf[ro + 4096];
  };
  auto mma8 = [&](const bf16x8* a4, const bf16x8* bj, int ibase, int j) {
#pragma unroll
    for (int ii = 0; ii < 4; ++ii)
#pragma unroll
      for (int kh = 0; kh < 2; ++kh)
        acc[ibase + ii][j] = __builtin_amdgcn_mfma_f32_16x16x32_bf16(
            bj[kh], a4[ii * 2 + kh], acc[ibase + ii][j], 0, 0, 0);
  };

  stageA(A0b, 0, 0); stageA(A0b, 1, 0);
  stageB(B0b, 0);
  stageA(A1b, 0, 64); stageA(A1b, 1, 64);
  __asm__ volatile("s_waitcnt vmcnt(4)" ::: "memory");
  S_BAR();

#pragma unroll 1
  for (int it = 0; it < 16; ++it) {
    const int kk = it * 128;
#pragma unroll
    for (int h = 0; h < 2; ++h) {
      u16* const Ab = h ? A1b : A0b;
      u16* const Bb = h ? B1b : B0b;
      u16* const Bo = h ? B0b : B1b;
      const int kB = (kk + 64 + h * 64) & 2047;
      const int kA = (kk + 128 + h * 64) & 2047;
      rdAh(aL, Ab, 0); rdBj(b0f, Bb, 0);
      stageB(Bo, kB);
      S_BAR(); LGKM0();
      __builtin_amdgcn_s_setprio(1); mma8(aL, b0f, 0, 0); __builtin_amdgcn_s_setprio(0);
      S_BAR();
      rdAh(aH, Ab, 4); rdBj(b1f, Bb, 1);
      S_BAR(); LGKM0();
      __builtin_amdgcn_s_setprio(1); mma8(aH, b0f, 4, 0); __builtin_amdgcn_s_setprio(0);
      S_BAR();
      stageA(Ab, 0, kA);
      S_BAR();
      __builtin_amdgcn_s_setprio(1); mma8(aH, b1f, 4, 1); __builtin_amdgcn_s_setprio(0);
      S_BAR();
      stageA(Ab, 1, kA);
      S_BAR();
      __builtin_amdgcn_s_setprio(1); mma8(aL, b1f, 0, 1); __builtin_amdgcn_s_setprio(0);
      VMC(4);
      S_BAR();
    }
  }

#pragma unroll
  for (int j = 0; j < 2; ++j) {
    const int nbase = n0 + wn + j * 16 + quad * 4;
    const float4 bsv = *(const float4*)&bias[nbase];
#pragma unroll
    for (int i = 0; i < 8; ++i) {
      const int m = m0 + wm + i * 16 + ln;
      float v0 = acc[i][j][0] + bsv.x, v1 = acc[i][j][1] + bsv.y;
      float v2 = acc[i][j][2] + bsv.z, v3 = acc[i][j][3] + bsv.w;
      if (fl) {
        float4 st = {v0, v1, v2, v3};
        *(float4*)&((float*)o0)[(size_t)m * 2048 + nbase] = st;
      } else {
        uint2 st; st.x = pack2bf(v0, v1); st.y = pack2bf(v2, v3);
        *(uint2*)&o0[(size_t)m * 2048 + nbase] = st;
      }
    }
  }
}

// =============== flash attention: 32x32 MFMA, in-register P, LDS-lean ===============
// (round-3 verified: ~49.8 us, passed R3+R5; grid (8,128), 4 blocks/CU)
__global__ __launch_bounds__(256, 4) void attn_kernel(
    const u16* __restrict__ q_ws, const u16* __restrict__ k_ws,
    const u16* __restrict__ vt_ws, u16* __restrict__ ctx) {
  __shared__ __align__(16) u16 lds[16384];
  const int tid = threadIdx.x;
  const int wave = tid >> 6, lane = tid & 63;
  const int l31 = lane & 31, hi = lane >> 5;
  const int sw = (l31 >> 1) & 3;
  const int qt = blockIdx.x, bh = blockIdx.y;
  const int b = bh >> 5, h = bh & 31, kvh = h >> 2;
  const int q0 = qt * 128 + wave * 32;
  const u16* const kptr = k_ws + (size_t)(b * 8 + kvh) * 65536;
  const u16* const vptr = vt_ws + (size_t)(b * 8 + kvh) * 65536;

  bf16x8 qf[4];
  {
    const size_t qb = (size_t)bh * 65536 + (size_t)(q0 + l31) * 64 + hi * 8;
#pragma unroll
    for (int ck = 0; ck < 4; ++ck) qf[ck] = *(const bf16x8*)&q_ws[qb + ck * 16];
  }

  const int strow = tid >> 2;
  const int stq = (tid & 3) ^ ((strow >> 1) & 3);
  const u16* const ks = kptr + strow * 64 + stq * 8;
  const u16* const vs = vptr + strow * 1024 + stq * 8;
  u16* const kd = &lds[tid * 8];
  u16* const vd = &lds[8192 + tid * 8];

  auto stageK = [&](int buf, int tile) {
    const u16* s = ks + tile * 4096;
    gl_lds16(s, kd + buf * 4096);
    gl_lds16(s + 32, kd + buf * 4096 + 2048);
  };
  auto stageV = [&](int buf, int tile) {
    const u16* s = vs + tile * 64;
    gl_lds16(s, vd + buf * 4096);
    gl_lds16(s + 32, vd + buf * 4096 + 2048);
  };

  f32x16 oacc0, oacc1;
#pragma unroll
  for (int r = 0; r < 16; ++r) { oacc0[r] = 0.f; oacc1[r] = 0.f; }
  float lsum = 0.f;

  auto qk = [&](int kh, int buf) -> f32x16 {
    f32x16 s;
#pragma unroll
    for (int r = 0; r < 16; ++r) s[r] = 0.f;
#pragma unroll
    for (int ck = 0; ck < 4; ++ck) {
      const int dq = (((ck & 1) << 1) | hi) ^ sw;
      bf16x8 kf = *(const bf16x8*)&lds[buf * 4096 + kh * 1024 + (ck >> 1) * 2048 +
                                       l31 * 32 + dq * 8];
      s = __builtin_amdgcn_mfma_f32_32x32x16_bf16(kf, qf[ck], s, 0, 0, 0);
    }
    return s;
  };

  auto softmax = [&](const f32x16& s, uint32_t* w) {
    float p[16];
#pragma unroll
    for (int r = 0; r < 16; ++r) p[r] = EXP2(s[r]);
    float t0 = (p[0] + p[1]) + (p[2] + p[3]);
    float t1 = (p[4] + p[5]) + (p[6] + p[7]);
    float t2 = (p[8] + p[9]) + (p[10] + p[11]);
    float t3 = (p[12] + p[13]) + (p[14] + p[15]);
    lsum += (t0 + t1) + (t2 + t3);
#pragma unroll
    for (int a = 0; a < 4; ++a) {
      w[a * 2 + 0] = cvt_pk_bf16(p[4 * a + 0], p[4 * a + 1]);
      w[a * 2 + 1] = cvt_pk_bf16(p[4 * a + 2], p[4 * a + 3]);
    }
  };

  auto pv = [&](uint32_t* w, int mm, int kh, int buf) {
    uint32_t x0 = w[4 * mm + 0], y0 = w[4 * mm + 2];
    uint32_t x1 = w[4 * mm + 1], y1 = w[4 * mm + 3];
    pl32_swap(x0, y0);
    pl32_swap(x1, y1);
    union { uint32_t u[4]; bf16x8 v; } pu;
    pu.u[0] = x0; pu.u[1] = x1; pu.u[2] = y0; pu.u[3] = y1;
    const int m = kh * 2 + mm;
    const int sq = ((((m & 1) << 1) | hi) ^ sw);
    const int vbase = 8192 + buf * 4096 + (m >> 1) * 2048 + l31 * 32 + sq * 8;
    bf16x8 vf0 = *(const bf16x8*)&lds[vbase];
    bf16x8 vf1 = *(const bf16x8*)&lds[vbase + 1024];
    oacc0 = __builtin_amdgcn_mfma_f32_32x32x16_bf16(pu.v, vf0, oacc0, 0, 0, 0);
    oacc1 = __builtin_amdgcn_mfma_f32_32x32x16_bf16(pu.v, vf1, oacc1, 0, 0, 0);
  };

  stageK(0, 0); stageV(0, 0);
  stageK(1, 1); stageV(1, 1);
  VMC(4);
  S_BAR();

#pragma unroll 1
  for (int it = 0; it < 16; ++it) {
    const int c = it & 1;
    f32x16 s0 = qk(0, c);
    uint32_t w0[8];
    softmax(s0, w0);
    pv(w0, 0, 0, c); pv(w0, 1, 0, c);
    f32x16 s1 = qk(1, c);
    uint32_t w1[8];
    softmax(s1, w1);
    pv(w1, 0, 1, c); pv(w1, 1, 1, c);
    if (it < 15) S_BAR();
    if (it < 14) {
      stageK(c, it + 2); stageV(c, it + 2);
      VMC(4);
      S_BAR();
    } else if (it == 14) {
      VMC(0);
      S_BAR();
    }
  }

  float lt = lsum + __shfl_xor(lsum, 32);
  const float inv = 1.0f / lt;
  const int ha = hi << 4;
  const size_t cb = (size_t)(b * 1024) * 2048 + (size_t)h * 64;
#pragma unroll
  for (int r = 0; r < 16; ++r) {
    const int qr = (r & 3) + 8 * (r >> 2);
    float iq = __uint_as_float(
        (uint32_t)__builtin_amdgcn_ds_bpermute(qr * 4 + ha, (int)__float_as_uint(inv)));
    const int q = q0 + qr + 4 * hi;
    const size_t rowb = cb + (size_t)q * 2048;
    ctx[rowb + l31]      = f2bf(oacc0[r] * iq);
    ctx[rowb + 32 + l31] = f2bf(oacc1[r] * iq);
  }
}

extern "C" void kernel_launch(void* const* d_in, const int* in_sizes, int n_in,
                              void* d_out, int out_size, void* d_ws, size_t ws_size,
                              hipStream_t stream) {
  const void* x  = d_in[0];
  const void* Wq = d_in[1];
  const void* bq = d_in[2];
  const void* Wk = d_in[3];
  const void* bk = d_in[4];
  const void* Wv = d_in[5];
  const void* bv = d_in[6];
  const void* Wo = d_in[7];
  const void* bo = d_in[8];
  char* ws = (char*)d_ws;

  u16* WT    = (u16*)(ws + 0);          // [3072][2048] bf16 (WqT|WkT|WvT)
  u16* WoT   = (u16*)(ws + 12582912);   // [2048][2048]
  u16* q_ws  = (u16*)(ws + 20971520);   // [4,32,1024,64]
  u16* k_ws  = (u16*)(ws + 37748736);   // [4,8,1024,64]
  u16* vt_ws = (u16*)(ws + 41943040);   // [4,8,64,1024]
  u16* c_ws  = (u16*)(ws + 46137344);   // [4096][2048]
  u16* xb    = (u16*)(ws + 62914560);   // [4096][2048] bf16 x
  float* biasf = (float*)(ws + 79691776); // 5120 fp32 packed biases
  int* flag  = (int*)(ws + 79712256);

  prep<<<4628, 256, 0, stream>>>(Wq, Wk, Wv, Wo, x, bq, bk, bv, bo,
                                 WT, WoT, xb, biasf, flag);

  gemm_qkv<<<dim3(8, 32), 512, 0, stream>>>(xb, WT, biasf, q_ws, k_ws, vt_ws);
  attn_kernel<<<dim3(8, 128), 256, 0, stream>>>(q_ws, k_ws, vt_ws, c_ws);
  gemm_o<<<dim3(16, 16), 512, 0, stream>>>(c_ws, WoT, biasf + 3072, (u16*)d_out, flag);
}

// Round 9
// 256.058 us; speedup vs baseline: 1.0761x; 1.0300x over previous
//
#include <hip/hip_runtime.h>
#include <stdint.h>

typedef unsigned short u16;
typedef __attribute__((ext_vector_type(8))) __bf16 bf16x8;
typedef __attribute__((ext_vector_type(4))) __bf16 bf16x4;
typedef __attribute__((ext_vector_type(4))) float f32x4;
typedef __attribute__((ext_vector_type(16))) float f32x16;

#define QSCALE 0.1803368801111204f  /* 0.125 * log2(e): S in log2 domain */

#if __has_builtin(__builtin_amdgcn_exp2f)
#define EXP2(x) __builtin_amdgcn_exp2f(x)
#else
#define EXP2(x) exp2f(x)
#endif

__device__ __forceinline__ u16 f2bf(float f) {
  uint32_t u = __float_as_uint(f);
  u += 0x7fffu + ((u >> 16) & 1u);
  return (u16)(u >> 16);
}
__device__ __forceinline__ float bf2f(u16 h) {
  return __uint_as_float(((uint32_t)h) << 16);
}
__device__ __forceinline__ uint32_t pack2bf(float a, float b) {
  return (uint32_t)f2bf(a) | ((uint32_t)f2bf(b) << 16);
}

__device__ __forceinline__ void gl_lds16(const u16* g, u16* l) {
  __builtin_amdgcn_global_load_lds(
      (const __attribute__((address_space(1))) unsigned int*)g,
      (__attribute__((address_space(3))) unsigned int*)l, 16, 0, 0);
}

__device__ __forceinline__ uint32_t cvt_pk_bf16(float lo, float hi) {
  uint32_t r;
  asm("v_cvt_pk_bf16_f32 %0, %1, %2" : "=v"(r) : "v"(lo), "v"(hi));
  return r;
}
// v_permlane32_swap_b32: x' = {x.lo, y.lo}, y' = {x.hi, y.hi} (lo/hi = lanes 0-31/32-63)
__device__ __forceinline__ void pl32_swap(uint32_t& x, uint32_t& y) {
  asm("v_permlane32_swap_b32 %0, %1" : "+v"(x), "+v"(y));
}

#define S_BAR() __builtin_amdgcn_s_barrier()
#define LGKM0() do { __asm__ volatile("s_waitcnt lgkmcnt(0)" ::: "memory"); \
                     __builtin_amdgcn_sched_barrier(0); } while (0)
#define VMC(N) do { __asm__ volatile("s_waitcnt vmcnt(" #N ")" ::: "memory"); \
                    __builtin_amdgcn_sched_barrier(0); } while (0)

// ---------------- dtype detector (separate kernel: R8 A/B showed fusion costs ~6 us) ----
__global__ void detect_dtype(const u16* __restrict__ x, int* __restrict__ flag) {
  __shared__ int any_huge;
  if (threadIdx.x == 0) any_huge = 0;
  __syncthreads();
  int huge = 0;
  for (int i = threadIdx.x; i < 4096; i += 256) {
    float v = bf2f(x[i]);
    if (!(fabsf(v) < 1e6f)) huge = 1;
  }
  if (huge) any_huge = 1;
  __syncthreads();
  if (threadIdx.x == 0) *flag = any_huge;  // 1 = inputs are fp32
}

// ---------------- fused prep (vectorized): weight transposes + x convert + biases ----
__global__ __launch_bounds__(256) void prep(
    const void* __restrict__ Wq, const void* __restrict__ Wk,
    const void* __restrict__ Wv, const void* __restrict__ Wo,
    const void* __restrict__ x,
    const void* __restrict__ bq, const void* __restrict__ bk,
    const void* __restrict__ bv, const void* __restrict__ bo,
    u16* __restrict__ WT, u16* __restrict__ WoT, u16* __restrict__ xb,
    float* __restrict__ biasf, const int* __restrict__ flag) {
  const int fl = *flag;
  int id = blockIdx.x;
  const int tid = threadIdx.x;
  if (id < 2560) {
    __shared__ u16 tile[64 * 72];
    const void* in; u16* outp; int N, rowoff;
    if (id < 1024)      { in = Wq; outp = WT;  N = 2048; rowoff = 0; }
    else if (id < 1280) { in = Wk; outp = WT;  N = 512;  rowoff = 2048; id -= 1024; }
    else if (id < 1536) { in = Wv; outp = WT;  N = 512;  rowoff = 2560; id -= 1280; }
    else                { in = Wo; outp = WoT; N = 2048; rowoff = 0;    id -= 1536; }
    int tiles_x = N >> 6;
    int nb = (id % tiles_x) * 64, kb = (id / tiles_x) * 64;
    const int kbase = (tid >> 4) * 4, nc = (tid & 15) * 4;
    if (fl) {
      float4 L[4];
#pragma unroll
      for (int p = 0; p < 4; ++p)
        L[p] = *(const float4*)&((const float*)in)[(size_t)(kb + kbase + p) * N + nb + nc];
#pragma unroll
      for (int nj = 0; nj < 4; ++nj) {
        uint2 w;
        w.x = pack2bf(((const float*)&L[0])[nj], ((const float*)&L[1])[nj]);
        w.y = pack2bf(((const float*)&L[2])[nj], ((const float*)&L[3])[nj]);
        *(uint2*)&tile[(nc + nj) * 72 + kbase] = w;
      }
    } else {
      uint2 L[4];
#pragma unroll
      for (int p = 0; p < 4; ++p)
        L[p] = *(const uint2*)&((const u16*)in)[(size_t)(kb + kbase + p) * N + nb + nc];
#pragma unroll
      for (int nj = 0; nj < 4; ++nj) {
        uint2 w;
        w.x = (uint32_t)((const u16*)&L[0])[nj] | ((uint32_t)((const u16*)&L[1])[nj] << 16);
        w.y = (uint32_t)((const u16*)&L[2])[nj] | ((uint32_t)((const u16*)&L[3])[nj] << 16);
        *(uint2*)&tile[(nc + nj) * 72 + kbase] = w;
      }
    }
    __syncthreads();
#pragma unroll
    for (int it = 0; it < 2; ++it) {
      int sid = it * 256 + tid;
      int row = sid >> 3, kseg = (sid & 7) * 8;
      uint4 v = *(const uint4*)&tile[row * 72 + kseg];
      *(uint4*)&outp[(size_t)(rowoff + nb + row) * 2048 + kb + kseg] = v;
    }
  } else if (id < 4608) {
    size_t base = ((size_t)(id - 2560) * 256 + tid) * 16;
    if (fl) {
      const float* xf = (const float*)x;
      float4 a = *(const float4*)&xf[base];
      float4 b = *(const float4*)&xf[base + 4];
      float4 c = *(const float4*)&xf[base + 8];
      float4 d = *(const float4*)&xf[base + 12];
      uint4 o0, o1;
      o0.x = pack2bf(a.x, a.y); o0.y = pack2bf(a.z, a.w);
      o0.z = pack2bf(b.x, b.y); o0.w = pack2bf(b.z, b.w);
      o1.x = pack2bf(c.x, c.y); o1.y = pack2bf(c.z, c.w);
      o1.z = pack2bf(d.x, d.y); o1.w = pack2bf(d.z, d.w);
      *(uint4*)&xb[base] = o0;
      *(uint4*)&xb[base + 8] = o1;
    } else {
      const u16* x16 = (const u16*)x;
      *(uint4*)&xb[base] = *(const uint4*)&x16[base];
      *(uint4*)&xb[base + 8] = *(const uint4*)&x16[base + 8];
    }
  } else {
    int i = (id - 4608) * 256 + tid;
    if (i < 5120) {
      const void* src; int idx;
      if (i < 2048)      { src = bq; idx = i; }
      else if (i < 2560) { src = bk; idx = i - 2048; }
      else if (i < 3072) { src = bv; idx = i - 2560; }
      else               { src = bo; idx = i - 3072; }
      biasf[i] = fl ? ((const float*)src)[idx] : bf2f(((const u16*)src)[idx]);
    }
  }
}

// =================== fused QKV projection: 128x384 tile, BK=64, 8 waves ===================
// R3 structure + per-phase counted VMC(6) (T4): issue cadence unchanged (2-2-2-2);
// drains staggered so every B-unit keeps 3-4 phases in flight, A keeps 5.
// Queue audit (steady state, 8 loads/half): each phase-end VMC(6) retires exactly the
// 2 oldest, which are always the loads consumed 1+ phase later behind a barrier.
__global__ __launch_bounds__(512, 2) void gemm_qkv(
    const u16* __restrict__ A, const u16* __restrict__ BT,
    const float* __restrict__ bias,
    u16* __restrict__ qo, u16* __restrict__ ko, u16* __restrict__ vo) {
  __shared__ __align__(16) u16 lds[65536];
  const int tid = threadIdx.x;
  const int wave = tid >> 6, lane = tid & 63;
  const int ln = lane & 15, quad = lane >> 4;
  const int sw8 = 8 * (quad ^ ((ln >> 1) & 3));
  const int m0 = blockIdx.y * 128, n0 = blockIdx.x * 384;

  u16* const A0b = lds;
  u16* const A1b = lds + 8192;
  u16* const B0b = lds + 16384;
  u16* const B1b = lds + 40960;

  const int srow = wave * 16 + (lane >> 2);
  const int skq = 8 * ((lane & 3) ^ ((lane >> 3) & 3));
  const u16* const sa = A + (size_t)(m0 + srow) * 2048 + skq;
  const u16* const sb = BT + (size_t)(n0 + srow) * 2048 + skq;
  const int dc8 = (wave * 64 + lane) * 8;

  auto stageA = [&](u16* dbase, int kt) {
    const u16* s = sa + kt;
    gl_lds16(s, dbase + dc8);
    gl_lds16(s + 32, dbase + dc8 + 4096);
  };
  auto stageB = [&](u16* dbase, int u, int kt) {
    const u16* s = sb + (size_t)u * 262144 + kt;
    u16* d = dbase + u * 4096 + dc8;
    gl_lds16(s, d);
    gl_lds16(s + 32, d + 12288);
  };

  f32x4 acc[8][3];
#pragma unroll
  for (int i = 0; i < 8; ++i)
#pragma unroll
    for (int j = 0; j < 3; ++j) acc[i][j] = {0.f, 0.f, 0.f, 0.f};

  bf16x8 aL[8], aH[8], b0f[2], b1f[2], b2f[2];
  auto rdAh = [&](bf16x8* dst, const u16* buf, int ibase) {
#pragma unroll
    for (int ii = 0; ii < 4; ++ii) {
      const int ro = ((ibase + ii) * 16 + ln) * 32 + sw8;
      dst[ii * 2 + 0] = *(const bf16x8*)&buf[ro];
      dst[ii * 2 + 1] = *(const bf16x8*)&buf[ro + 4096];
    }
  };
  auto rdBj = [&](bf16x8* dst, const u16* buf, int j) {
    const int ro = (wave * 48 + j * 16 + ln) * 32 + sw8;
    dst[0] = *(const bf16x8*)&buf[ro];
    dst[1] = *(const bf16x8*)&buf[ro + 12288];
  };
  auto mma8 = [&](const bf16x8* a4, const bf16x8* bj, int ibase, int j) {
#pragma unroll
    for (int ii = 0; ii < 4; ++ii)
#pragma unroll
      for (int kh = 0; kh < 2; ++kh)
        acc[ibase + ii][j] = __builtin_amdgcn_mfma_f32_16x16x32_bf16(
            bj[kh], a4[ii * 2 + kh], acc[ibase + ii][j], 0, 0, 0);
  };

  stageA(A0b, 0);
  stageB(B0b, 0, 0); stageB(B0b, 1, 0); stageB(B0b, 2, 0);
  stageA(A1b, 64);
  __asm__ volatile("s_waitcnt vmcnt(2)" ::: "memory");
  S_BAR();

#pragma unroll 1
  for (int it = 0; it < 16; ++it) {
    const int kk = it * 128;
#pragma unroll
    for (int h = 0; h < 2; ++h) {
      u16* const Ab = h ? A1b : A0b;
      u16* const Bb = h ? B1b : B0b;
      u16* const Bo = h ? B0b : B1b;
      const int kB = (kk + 64 + h * 64) & 2047;
      const int kA = (kk + 128 + h * 64) & 2047;
      rdAh(aL, Ab, 0); rdBj(b0f, Bb, 0);
      stageB(Bo, 0, kB);
      S_BAR(); LGKM0();
      __builtin_amdgcn_s_setprio(1); mma8(aL, b0f, 0, 0); __builtin_amdgcn_s_setprio(0);
      VMC(6);
      S_BAR();
      rdAh(aH, Ab, 4); rdBj(b1f, Bb, 1);
      stageB(Bo, 1, kB);
      S_BAR(); LGKM0();
      __builtin_amdgcn_s_setprio(1); mma8(aH, b0f, 4, 0); mma8(aL, b1f, 0, 1); __builtin_amdgcn_s_setprio(0);
      VMC(6);
      S_BAR();
      rdBj(b2f, Bb, 2);
      stageB(Bo, 2, kB);
      S_BAR(); LGKM0();
      __builtin_amdgcn_s_setprio(1); mma8(aH, b1f, 4, 1); mma8(aL, b2f, 0, 2); __builtin_amdgcn_s_setprio(0);
      VMC(6);
      S_BAR();
      stageA(Ab, kA);
      S_BAR();
      __builtin_amdgcn_s_setprio(1); mma8(aH, b2f, 4, 2); __builtin_amdgcn_s_setprio(0);
      VMC(6);
      S_BAR();
    }
  }

#pragma unroll
  for (int j = 0; j < 3; ++j) {
    const int gnf = n0 + wave * 48 + j * 16;
    const int gn = gnf + quad * 4;
    const float4 bsv = *(const float4*)&bias[gn];
    if (gnf < 2048) {
      const int hh = gn >> 6, dd = gn & 63;
#pragma unroll
      for (int i = 0; i < 8; ++i) {
        const int m = m0 + i * 16 + ln;
        const int b = m >> 10, s = m & 1023;
        uint2 st;
        st.x = pack2bf((acc[i][j][0] + bsv.x) * QSCALE, (acc[i][j][1] + bsv.y) * QSCALE);
        st.y = pack2bf((acc[i][j][2] + bsv.z) * QSCALE, (acc[i][j][3] + bsv.w) * QSCALE);
        *(uint2*)&qo[(((size_t)(b * 32 + hh)) * 1024 + s) * 64 + dd] = st;
      }
    } else if (gnf < 2560) {
      const int n2 = gn - 2048, hh = n2 >> 6, dd = n2 & 63;
#pragma unroll
      for (int i = 0; i < 8; ++i) {
        const int m = m0 + i * 16 + ln;
        const int b = m >> 10, s = m & 1023;
        uint2 st;
        st.x = pack2bf(acc[i][j][0] + bsv.x, acc[i][j][1] + bsv.y);
        st.y = pack2bf(acc[i][j][2] + bsv.z, acc[i][j][3] + bsv.w);
        *(uint2*)&ko[(((size_t)(b * 8 + hh)) * 1024 + s) * 64 + dd] = st;
      }
    } else {
      const int n2 = gn - 2560, hh = n2 >> 6, dd0 = n2 & 63;
#pragma unroll
      for (int i = 0; i < 8; ++i) {
        const int m = m0 + i * 16 + ln;
        const int b = m >> 10, s = m & 1023;
        const size_t vb = ((size_t)(b * 8 + hh) * 64 + dd0) * 1024 + s;
        vo[vb]        = f2bf(acc[i][j][0] + bsv.x);
        vo[vb + 1024] = f2bf(acc[i][j][1] + bsv.y);
        vo[vb + 2048] = f2bf(acc[i][j][2] + bsv.z);
        vo[vb + 3072] = f2bf(acc[i][j][3] + bsv.w);
      }
    }
  }
}

// =================== O projection: 256x128 tile, BK=64, 8 waves ===================
// (round-3 verified; drain audit: B 3-phase slack, A 4-phase with single VMC(4) - kept)
__global__ __launch_bounds__(512, 2) void gemm_o(
    const u16* __restrict__ A, const u16* __restrict__ BT,
    const float* __restrict__ bias, u16* __restrict__ o0,
    const int* __restrict__ flag) {
  __shared__ __align__(16) u16 lds[49152];
  const int tid = threadIdx.x;
  const int wave = tid >> 6, lane = tid & 63;
  const int ln = lane & 15, quad = lane >> 4;
  const int sw8 = 8 * (quad ^ ((ln >> 1) & 3));
  const int wm = (wave >> 2) * 128, wn = (wave & 3) * 32;
  const int m0 = blockIdx.y * 256, n0 = blockIdx.x * 128;
  const int fl = *flag;

  u16* const A0b = lds;
  u16* const A1b = lds + 16384;
  u16* const B0b = lds + 32768;
  u16* const B1b = lds + 40960;

  const int srow = wave * 16 + (lane >> 2);
  const int skq = 8 * ((lane & 3) ^ ((lane >> 3) & 3));
  const u16* const sa = A + (size_t)(m0 + srow) * 2048 + skq;
  const u16* const sb = BT + (size_t)(n0 + srow) * 2048 + skq;
  const int dc8 = (wave * 64 + lane) * 8;

  auto stageA = [&](u16* dbase, int H, int kt) {
    const u16* s = sa + (size_t)H * 262144 + kt;
    u16* d = dbase + H * 4096 + dc8;
    gl_lds16(s, d);
    gl_lds16(s + 32, d + 8192);
  };
  auto stageB = [&](u16* dbase, int kt) {
    const u16* s = sb + kt;
    gl_lds16(s, dbase + dc8);
    gl_lds16(s + 32, dbase + dc8 + 4096);
  };

  f32x4 acc[8][2];
#pragma unroll
  for (int i = 0; i < 8; ++i)
#pragma unroll
    for (int j = 0; j < 2; ++j) acc[i][j] = {0.f, 0.f, 0.f, 0.f};

  bf16x8 aL[8], aH[8], b0f[2], b1f[2];
  auto rdAh = [&](bf16x8* dst, const u16* buf, int ibase) {
#pragma unroll
    for (int ii = 0; ii < 4; ++ii) {
      const int ro = (wm + (ibase + ii) * 16 + ln) * 32 + sw8;
      dst[ii * 2 + 0] = *(const bf16x8*)&buf[ro];
      dst[ii * 2 + 1] = *(const bf16x8*)&buf[ro + 8192];
    }
  };
  auto rdBj = [&](bf16x8* dst, const u16* buf, int j) {
    const int ro = (wn + j * 16 + ln) * 32 + sw8;
    dst[0] = *(const bf16x8*)&buf[ro];
    dst[1] = *(const bf16x8*)&buf[ro + 4096];
  };
  auto mma8 = [&](const bf16x8* a4, const bf16x8* bj, int ibase, int j) {
#pragma unroll
    for (int ii = 0; ii < 4; ++ii)
#pragma unroll
      for (int kh = 0; kh < 2; ++kh)
        acc[ibase + ii][j] = __builtin_amdgcn_mfma_f32_16x16x32_bf16(
            bj[kh], a4[ii * 2 + kh], acc[ibase + ii][j], 0, 0, 0);
  };

  stageA(A0b, 0, 0); stageA(A0b, 1, 0);
  stageB(B0b, 0);
  stageA(A1b, 0, 64); stageA(A1b, 1, 64);
  __asm__ volatile("s_waitcnt vmcnt(4)" ::: "memory");
  S_BAR();

#pragma unroll 1
  for (int it = 0; it < 16; ++it) {
    const int kk = it * 128;
#pragma unroll
    for (int h = 0; h < 2; ++h) {
      u16* const Ab = h ? A1b : A0b;
      u16* const Bb = h ? B1b : B0b;
      u16* const Bo = h ? B0b : B1b;
      const int kB = (kk + 64 + h * 64) & 2047;
      const int kA = (kk + 128 + h * 64) & 2047;
      rdAh(aL, Ab, 0); rdBj(b0f, Bb, 0);
      stageB(Bo, kB);
      S_BAR(); LGKM0();
      __builtin_amdgcn_s_setprio(1); mma8(aL, b0f, 0, 0); __builtin_amdgcn_s_setprio(0);
      S_BAR();
      rdAh(aH, Ab, 4); rdBj(b1f, Bb, 1);
      S_BAR(); LGKM0();
      __builtin_amdgcn_s_setprio(1); mma8(aH, b0f, 4, 0); __builtin_amdgcn_s_setprio(0);
      S_BAR();
      stageA(Ab, 0, kA);
      S_BAR();
      __builtin_amdgcn_s_setprio(1); mma8(aH, b1f, 4, 1); __builtin_amdgcn_s_setprio(0);
      S_BAR();
      stageA(Ab, 1, kA);
      S_BAR();
      __builtin_amdgcn_s_setprio(1); mma8(aL, b1f, 0, 1); __builtin_amdgcn_s_setprio(0);
      VMC(4);
      S_BAR();
    }
  }

#pragma unroll
  for (int j = 0; j < 2; ++j) {
    const int nbase = n0 + wn + j * 16 + quad * 4;
    const float4 bsv = *(const float4*)&bias[nbase];
#pragma unroll
    for (int i = 0; i < 8; ++i) {
      const int m = m0 + wm + i * 16 + ln;
      float v0 = acc[i][j][0] + bsv.x, v1 = acc[i][j][1] + bsv.y;
      float v2 = acc[i][j][2] + bsv.z, v3 = acc[i][j][3] + bsv.w;
      if (fl) {
        float4 st = {v0, v1, v2, v3};
        *(float4*)&((float*)o0)[(size_t)m * 2048 + nbase] = st;
      } else {
        uint2 st; st.x = pack2bf(v0, v1); st.y = pack2bf(v2, v3);
        *(uint2*)&o0[(size_t)m * 2048 + nbase] = st;
      }
    }
  }
}

// =============== flash attention: 32x32 MFMA, in-register P, LDS-lean ===============
// (round-3 verified: passed R3+R5; grid (8,128), 4 blocks/CU)
__global__ __launch_bounds__(256, 4) void attn_kernel(
    const u16* __restrict__ q_ws, const u16* __restrict__ k_ws,
    const u16* __restrict__ vt_ws, u16* __restrict__ ctx) {
  __shared__ __align__(16) u16 lds[16384];
  const int tid = threadIdx.x;
  const int wave = tid >> 6, lane = tid & 63;
  const int l31 = lane & 31, hi = lane >> 5;
  const int sw = (l31 >> 1) & 3;
  const int qt = blockIdx.x, bh = blockIdx.y;
  const int b = bh >> 5, h = bh & 31, kvh = h >> 2;
  const int q0 = qt * 128 + wave * 32;
  const u16* const kptr = k_ws + (size_t)(b * 8 + kvh) * 65536;
  const u16* const vptr = vt_ws + (size_t)(b * 8 + kvh) * 65536;

  bf16x8 qf[4];
  {
    const size_t qb = (size_t)bh * 65536 + (size_t)(q0 + l31) * 64 + hi * 8;
#pragma unroll
    for (int ck = 0; ck < 4; ++ck) qf[ck] = *(const bf16x8*)&q_ws[qb + ck * 16];
  }

  const int strow = tid >> 2;
  const int stq = (tid & 3) ^ ((strow >> 1) & 3);
  const u16* const ks = kptr + strow * 64 + stq * 8;
  const u16* const vs = vptr + strow * 1024 + stq * 8;
  u16* const kd = &lds[tid * 8];
  u16* const vd = &lds[8192 + tid * 8];

  auto stageK = [&](int buf, int tile) {
    const u16* s = ks + tile * 4096;
    gl_lds16(s, kd + buf * 4096);
    gl_lds16(s + 32, kd + buf * 4096 + 2048);
  };
  auto stageV = [&](int buf, int tile) {
    const u16* s = vs + tile * 64;
    gl_lds16(s, vd + buf * 4096);
    gl_lds16(s + 32, vd + buf * 4096 + 2048);
  };

  f32x16 oacc0, oacc1;
#pragma unroll
  for (int r = 0; r < 16; ++r) { oacc0[r] = 0.f; oacc1[r] = 0.f; }
  float lsum = 0.f;

  auto qk = [&](int kh, int buf) -> f32x16 {
    f32x16 s;
#pragma unroll
    for (int r = 0; r < 16; ++r) s[r] = 0.f;
#pragma unroll
    for (int ck = 0; ck < 4; ++ck) {
      const int dq = (((ck & 1) << 1) | hi) ^ sw;
      bf16x8 kf = *(const bf16x8*)&lds[buf * 4096 + kh * 1024 + (ck >> 1) * 2048 +
                                       l31 * 32 + dq * 8];
      s = __builtin_amdgcn_mfma_f32_32x32x16_bf16(kf, qf[ck], s, 0, 0, 0);
    }
    return s;
  };

  auto softmax = [&](const f32x16& s, uint32_t* w) {
    float p[16];
#pragma unroll
    for (int r = 0; r < 16; ++r) p[r] = EXP2(s[r]);
    float t0 = (p[0] + p[1]) + (p[2] + p[3]);
    float t1 = (p[4] + p[5]) + (p[6] + p[7]);
    float t2 = (p[8] + p[9]) + (p[10] + p[11]);
    float t3 = (p[12] + p[13]) + (p[14] + p[15]);
    lsum += (t0 + t1) + (t2 + t3);
#pragma unroll
    for (int a = 0; a < 4; ++a) {
      w[a * 2 + 0] = cvt_pk_bf16(p[4 * a + 0], p[4 * a + 1]);
      w[a * 2 + 1] = cvt_pk_bf16(p[4 * a + 2], p[4 * a + 3]);
    }
  };

  auto pv = [&](uint32_t* w, int mm, int kh, int buf) {
    uint32_t x0 = w[4 * mm + 0], y0 = w[4 * mm + 2];
    uint32_t x1 = w[4 * mm + 1], y1 = w[4 * mm + 3];
    pl32_swap(x0, y0);
    pl32_swap(x1, y1);
    union { uint32_t u[4]; bf16x8 v; } pu;
    pu.u[0] = x0; pu.u[1] = x1; pu.u[2] = y0; pu.u[3] = y1;
    const int m = kh * 2 + mm;
    const int sq = ((((m & 1) << 1) | hi) ^ sw);
    const int vbase = 8192 + buf * 4096 + (m >> 1) * 2048 + l31 * 32 + sq * 8;
    bf16x8 vf0 = *(const bf16x8*)&lds[vbase];
    bf16x8 vf1 = *(const bf16x8*)&lds[vbase + 1024];
    oacc0 = __builtin_amdgcn_mfma_f32_32x32x16_bf16(pu.v, vf0, oacc0, 0, 0, 0);
    oacc1 = __builtin_amdgcn_mfma_f32_32x32x16_bf16(pu.v, vf1, oacc1, 0, 0, 0);
  };

  stageK(0, 0); stageV(0, 0);
  stageK(1, 1); stageV(1, 1);
  VMC(4);
  S_BAR();

#pragma unroll 1
  for (int it = 0; it < 16; ++it) {
    const int c = it & 1;
    f32x16 s0 = qk(0, c);
    uint32_t w0[8];
    softmax(s0, w0);
    pv(w0, 0, 0, c); pv(w0, 1, 0, c);
    f32x16 s1 = qk(1, c);
    uint32_t w1[8];
    softmax(s1, w1);
    pv(w1, 0, 1, c); pv(w1, 1, 1, c);
    if (it < 15) S_BAR();
    if (it < 14) {
      stageK(c, it + 2); stageV(c, it + 2);
      VMC(4);
      S_BAR();
    } else if (it == 14) {
      VMC(0);
      S_BAR();
    }
  }

  float lt = lsum + __shfl_xor(lsum, 32);
  const float inv = 1.0f / lt;
  const int ha = hi << 4;
  const size_t cb = (size_t)(b * 1024) * 2048 + (size_t)h * 64;
#pragma unroll
  for (int r = 0; r < 16; ++r) {
    const int qr = (r & 3) + 8 * (r >> 2);
    float iq = __uint_as_float(
        (uint32_t)__builtin_amdgcn_ds_bpermute(qr * 4 + ha, (int)__float_as_uint(inv)));
    const int q = q0 + qr + 4 * hi;
    const size_t rowb = cb + (size_t)q * 2048;
    ctx[rowb + l31]      = f2bf(oacc0[r] * iq);
    ctx[rowb + 32 + l31] = f2bf(oacc1[r] * iq);
  }
}

extern "C" void kernel_launch(void* const* d_in, const int* in_sizes, int n_in,
                              void* d_out, int out_size, void* d_ws, size_t ws_size,
                              hipStream_t stream) {
  const void* x  = d_in[0];
  const void* Wq = d_in[1];
  const void* bq = d_in[2];
  const void* Wk = d_in[3];
  const void* bk = d_in[4];
  const void* Wv = d_in[5];
  const void* bv = d_in[6];
  const void* Wo = d_in[7];
  const void* bo = d_in[8];
  char* ws = (char*)d_ws;

  u16* WT    = (u16*)(ws + 0);          // [3072][2048] bf16 (WqT|WkT|WvT)
  u16* WoT   = (u16*)(ws + 12582912);   // [2048][2048]
  u16* q_ws  = (u16*)(ws + 20971520);   // [4,32,1024,64]
  u16* k_ws  = (u16*)(ws + 37748736);   // [4,8,1024,64]
  u16* vt_ws = (u16*)(ws + 41943040);   // [4,8,64,1024]
  u16* c_ws  = (u16*)(ws + 46137344);   // [4096][2048]
  u16* xb    = (u16*)(ws + 62914560);   // [4096][2048] bf16 x
  float* biasf = (float*)(ws + 79691776); // 5120 fp32 packed biases
  int* flag  = (int*)(ws + 79712256);

  detect_dtype<<<1, 256, 0, stream>>>((const u16*)x, flag);
  prep<<<4628, 256, 0, stream>>>(Wq, Wk, Wv, Wo, x, bq, bk, bv, bo,
                                 WT, WoT, xb, biasf, flag);

  gemm_qkv<<<dim3(8, 32), 512, 0, stream>>>(xb, WT, biasf, q_ws, k_ws, vt_ws);
  attn_kernel<<<dim3(8, 128), 256, 0, stream>>>(q_ws, k_ws, vt_ws, c_ws);
  gemm_o<<<dim3(16, 16), 512, 0, stream>>>(c_ws, WoT, biasf + 3072, (u16*)d_out, flag);
}

// Round 10
// 251.355 us; speedup vs baseline: 1.0962x; 1.0187x over previous
//
#include <hip/hip_runtime.h>
#include <stdint.h>

typedef unsigned short u16;
typedef __attribute__((ext_vector_type(8))) __bf16 bf16x8;
typedef __attribute__((ext_vector_type(4))) __bf16 bf16x4;
typedef __attribute__((ext_vector_type(4))) float f32x4;
typedef __attribute__((ext_vector_type(16))) float f32x16;

#define QSCALE 0.1803368801111204f  /* 0.125 * log2(e): S in log2 domain */

#if __has_builtin(__builtin_amdgcn_exp2f)
#define EXP2(x) __builtin_amdgcn_exp2f(x)
#else
#define EXP2(x) exp2f(x)
#endif

__device__ __forceinline__ u16 f2bf(float f) {
  uint32_t u = __float_as_uint(f);
  u += 0x7fffu + ((u >> 16) & 1u);
  return (u16)(u >> 16);
}
__device__ __forceinline__ float bf2f(u16 h) {
  return __uint_as_float(((uint32_t)h) << 16);
}
__device__ __forceinline__ uint32_t pack2bf(float a, float b) {
  return (uint32_t)f2bf(a) | ((uint32_t)f2bf(b) << 16);
}

__device__ __forceinline__ void gl_lds16(const u16* g, u16* l) {
  __builtin_amdgcn_global_load_lds(
      (const __attribute__((address_space(1))) unsigned int*)g,
      (__attribute__((address_space(3))) unsigned int*)l, 16, 0, 0);
}

__device__ __forceinline__ uint32_t cvt_pk_bf16(float lo, float hi) {
  uint32_t r;
  asm("v_cvt_pk_bf16_f32 %0, %1, %2" : "=v"(r) : "v"(lo), "v"(hi));
  return r;
}
// v_permlane32_swap_b32: x' = {x.lo, y.lo}, y' = {x.hi, y.hi} (lo/hi = lanes 0-31/32-63)
__device__ __forceinline__ void pl32_swap(uint32_t& x, uint32_t& y) {
  asm("v_permlane32_swap_b32 %0, %1" : "+v"(x), "+v"(y));
}

#define S_BAR() __builtin_amdgcn_s_barrier()
#define LGKM0() do { __asm__ volatile("s_waitcnt lgkmcnt(0)" ::: "memory"); \
                     __builtin_amdgcn_sched_barrier(0); } while (0)
#define VMC(N) do { __asm__ volatile("s_waitcnt vmcnt(" #N ")" ::: "memory"); \
                    __builtin_amdgcn_sched_barrier(0); } while (0)

// ---------------- dtype detector (separate kernel: R8 A/B showed fusion costs ~6 us) ----
__global__ void detect_dtype(const u16* __restrict__ x, int* __restrict__ flag) {
  __shared__ int any_huge;
  if (threadIdx.x == 0) any_huge = 0;
  __syncthreads();
  int huge = 0;
  for (int i = threadIdx.x; i < 4096; i += 256) {
    float v = bf2f(x[i]);
    if (!(fabsf(v) < 1e6f)) huge = 1;
  }
  if (huge) any_huge = 1;
  __syncthreads();
  if (threadIdx.x == 0) *flag = any_huge;  // 1 = inputs are fp32
}

// ---------------- fused prep (vectorized): weight transposes + x convert + biases ----
__global__ __launch_bounds__(256) void prep(
    const void* __restrict__ Wq, const void* __restrict__ Wk,
    const void* __restrict__ Wv, const void* __restrict__ Wo,
    const void* __restrict__ x,
    const void* __restrict__ bq, const void* __restrict__ bk,
    const void* __restrict__ bv, const void* __restrict__ bo,
    u16* __restrict__ WT, u16* __restrict__ WoT, u16* __restrict__ xb,
    float* __restrict__ biasf, const int* __restrict__ flag) {
  const int fl = *flag;
  int id = blockIdx.x;
  const int tid = threadIdx.x;
  if (id < 2560) {
    __shared__ u16 tile[64 * 72];
    const void* in; u16* outp; int N, rowoff;
    if (id < 1024)      { in = Wq; outp = WT;  N = 2048; rowoff = 0; }
    else if (id < 1280) { in = Wk; outp = WT;  N = 512;  rowoff = 2048; id -= 1024; }
    else if (id < 1536) { in = Wv; outp = WT;  N = 512;  rowoff = 2560; id -= 1280; }
    else                { in = Wo; outp = WoT; N = 2048; rowoff = 0;    id -= 1536; }
    int tiles_x = N >> 6;
    int nb = (id % tiles_x) * 64, kb = (id / tiles_x) * 64;
    const int kbase = (tid >> 4) * 4, nc = (tid & 15) * 4;
    if (fl) {
      float4 L[4];
#pragma unroll
      for (int p = 0; p < 4; ++p)
        L[p] = *(const float4*)&((const float*)in)[(size_t)(kb + kbase + p) * N + nb + nc];
#pragma unroll
      for (int nj = 0; nj < 4; ++nj) {
        uint2 w;
        w.x = pack2bf(((const float*)&L[0])[nj], ((const float*)&L[1])[nj]);
        w.y = pack2bf(((const float*)&L[2])[nj], ((const float*)&L[3])[nj]);
        *(uint2*)&tile[(nc + nj) * 72 + kbase] = w;
      }
    } else {
      uint2 L[4];
#pragma unroll
      for (int p = 0; p < 4; ++p)
        L[p] = *(const uint2*)&((const u16*)in)[(size_t)(kb + kbase + p) * N + nb + nc];
#pragma unroll
      for (int nj = 0; nj < 4; ++nj) {
        uint2 w;
        w.x = (uint32_t)((const u16*)&L[0])[nj] | ((uint32_t)((const u16*)&L[1])[nj] << 16);
        w.y = (uint32_t)((const u16*)&L[2])[nj] | ((uint32_t)((const u16*)&L[3])[nj] << 16);
        *(uint2*)&tile[(nc + nj) * 72 + kbase] = w;
      }
    }
    __syncthreads();
#pragma unroll
    for (int it = 0; it < 2; ++it) {
      int sid = it * 256 + tid;
      int row = sid >> 3, kseg = (sid & 7) * 8;
      uint4 v = *(const uint4*)&tile[row * 72 + kseg];
      *(uint4*)&outp[(size_t)(rowoff + nb + row) * 2048 + kb + kseg] = v;
    }
  } else if (id < 4608) {
    size_t base = ((size_t)(id - 2560) * 256 + tid) * 16;
    if (fl) {
      const float* xf = (const float*)x;
      float4 a = *(const float4*)&xf[base];
      float4 b = *(const float4*)&xf[base + 4];
      float4 c = *(const float4*)&xf[base + 8];
      float4 d = *(const float4*)&xf[base + 12];
      uint4 o0, o1;
      o0.x = pack2bf(a.x, a.y); o0.y = pack2bf(a.z, a.w);
      o0.z = pack2bf(b.x, b.y); o0.w = pack2bf(b.z, b.w);
      o1.x = pack2bf(c.x, c.y); o1.y = pack2bf(c.z, c.w);
      o1.z = pack2bf(d.x, d.y); o1.w = pack2bf(d.z, d.w);
      *(uint4*)&xb[base] = o0;
      *(uint4*)&xb[base + 8] = o1;
    } else {
      const u16* x16 = (const u16*)x;
      *(uint4*)&xb[base] = *(const uint4*)&x16[base];
      *(uint4*)&xb[base + 8] = *(const uint4*)&x16[base + 8];
    }
  } else {
    int i = (id - 4608) * 256 + tid;
    if (i < 5120) {
      const void* src; int idx;
      if (i < 2048)      { src = bq; idx = i; }
      else if (i < 2560) { src = bk; idx = i - 2048; }
      else if (i < 3072) { src = bv; idx = i - 2560; }
      else               { src = bo; idx = i - 3072; }
      biasf[i] = fl ? ((const float*)src)[idx] : bf2f(((const u16*)src)[idx]);
    }
  }
}

// =================== fused QKV projection: 128x384 tile, BK=64, 8 waves ===================
// (round-3 verified optimum: 59.4 us; R9's per-phase VMC(6) regressed -> reverted)
__global__ __launch_bounds__(512, 2) void gemm_qkv(
    const u16* __restrict__ A, const u16* __restrict__ BT,
    const float* __restrict__ bias,
    u16* __restrict__ qo, u16* __restrict__ ko, u16* __restrict__ vo) {
  __shared__ __align__(16) u16 lds[65536];
  const int tid = threadIdx.x;
  const int wave = tid >> 6, lane = tid & 63;
  const int ln = lane & 15, quad = lane >> 4;
  const int sw8 = 8 * (quad ^ ((ln >> 1) & 3));
  const int m0 = blockIdx.y * 128, n0 = blockIdx.x * 384;

  u16* const A0b = lds;
  u16* const A1b = lds + 8192;
  u16* const B0b = lds + 16384;
  u16* const B1b = lds + 40960;

  const int srow = wave * 16 + (lane >> 2);
  const int skq = 8 * ((lane & 3) ^ ((lane >> 3) & 3));
  const u16* const sa = A + (size_t)(m0 + srow) * 2048 + skq;
  const u16* const sb = BT + (size_t)(n0 + srow) * 2048 + skq;
  const int dc8 = (wave * 64 + lane) * 8;

  auto stageA = [&](u16* dbase, int kt) {
    const u16* s = sa + kt;
    gl_lds16(s, dbase + dc8);
    gl_lds16(s + 32, dbase + dc8 + 4096);
  };
  auto stageB = [&](u16* dbase, int u, int kt) {
    const u16* s = sb + (size_t)u * 262144 + kt;
    u16* d = dbase + u * 4096 + dc8;
    gl_lds16(s, d);
    gl_lds16(s + 32, d + 12288);
  };

  f32x4 acc[8][3];
#pragma unroll
  for (int i = 0; i < 8; ++i)
#pragma unroll
    for (int j = 0; j < 3; ++j) acc[i][j] = {0.f, 0.f, 0.f, 0.f};

  bf16x8 aL[8], aH[8], b0f[2], b1f[2], b2f[2];
  auto rdAh = [&](bf16x8* dst, const u16* buf, int ibase) {
#pragma unroll
    for (int ii = 0; ii < 4; ++ii) {
      const int ro = ((ibase + ii) * 16 + ln) * 32 + sw8;
      dst[ii * 2 + 0] = *(const bf16x8*)&buf[ro];
      dst[ii * 2 + 1] = *(const bf16x8*)&buf[ro + 4096];
    }
  };
  auto rdBj = [&](bf16x8* dst, const u16* buf, int j) {
    const int ro = (wave * 48 + j * 16 + ln) * 32 + sw8;
    dst[0] = *(const bf16x8*)&buf[ro];
    dst[1] = *(const bf16x8*)&buf[ro + 12288];
  };
  auto mma8 = [&](const bf16x8* a4, const bf16x8* bj, int ibase, int j) {
#pragma unroll
    for (int ii = 0; ii < 4; ++ii)
#pragma unroll
      for (int kh = 0; kh < 2; ++kh)
        acc[ibase + ii][j] = __builtin_amdgcn_mfma_f32_16x16x32_bf16(
            bj[kh], a4[ii * 2 + kh], acc[ibase + ii][j], 0, 0, 0);
  };

  stageA(A0b, 0);
  stageB(B0b, 0, 0); stageB(B0b, 1, 0); stageB(B0b, 2, 0);
  stageA(A1b, 64);
  __asm__ volatile("s_waitcnt vmcnt(2)" ::: "memory");
  S_BAR();

#pragma unroll 1
  for (int it = 0; it < 16; ++it) {
    const int kk = it * 128;
#pragma unroll
    for (int h = 0; h < 2; ++h) {
      u16* const Ab = h ? A1b : A0b;
      u16* const Bb = h ? B1b : B0b;
      u16* const Bo = h ? B0b : B1b;
      const int kB = (kk + 64 + h * 64) & 2047;
      const int kA = (kk + 128 + h * 64) & 2047;
      rdAh(aL, Ab, 0); rdBj(b0f, Bb, 0);
      stageB(Bo, 0, kB);
      S_BAR(); LGKM0();
      __builtin_amdgcn_s_setprio(1); mma8(aL, b0f, 0, 0); __builtin_amdgcn_s_setprio(0);
      S_BAR();
      rdAh(aH, Ab, 4); rdBj(b1f, Bb, 1);
      stageB(Bo, 1, kB);
      S_BAR(); LGKM0();
      __builtin_amdgcn_s_setprio(1); mma8(aH, b0f, 4, 0); mma8(aL, b1f, 0, 1); __builtin_amdgcn_s_setprio(0);
      S_BAR();
      rdBj(b2f, Bb, 2);
      stageB(Bo, 2, kB);
      S_BAR(); LGKM0();
      __builtin_amdgcn_s_setprio(1); mma8(aH, b1f, 4, 1); mma8(aL, b2f, 0, 2); __builtin_amdgcn_s_setprio(0);
      S_BAR();
      stageA(Ab, kA);
      S_BAR();
      __builtin_amdgcn_s_setprio(1); mma8(aH, b2f, 4, 2); __builtin_amdgcn_s_setprio(0);
      VMC(2);
      S_BAR();
    }
  }

#pragma unroll
  for (int j = 0; j < 3; ++j) {
    const int gnf = n0 + wave * 48 + j * 16;
    const int gn = gnf + quad * 4;
    const float4 bsv = *(const float4*)&bias[gn];
    if (gnf < 2048) {
      const int hh = gn >> 6, dd = gn & 63;
#pragma unroll
      for (int i = 0; i < 8; ++i) {
        const int m = m0 + i * 16 + ln;
        const int b = m >> 10, s = m & 1023;
        uint2 st;
        st.x = pack2bf((acc[i][j][0] + bsv.x) * QSCALE, (acc[i][j][1] + bsv.y) * QSCALE);
        st.y = pack2bf((acc[i][j][2] + bsv.z) * QSCALE, (acc[i][j][3] + bsv.w) * QSCALE);
        *(uint2*)&qo[(((size_t)(b * 32 + hh)) * 1024 + s) * 64 + dd] = st;
      }
    } else if (gnf < 2560) {
      const int n2 = gn - 2048, hh = n2 >> 6, dd = n2 & 63;
#pragma unroll
      for (int i = 0; i < 8; ++i) {
        const int m = m0 + i * 16 + ln;
        const int b = m >> 10, s = m & 1023;
        uint2 st;
        st.x = pack2bf(acc[i][j][0] + bsv.x, acc[i][j][1] + bsv.y);
        st.y = pack2bf(acc[i][j][2] + bsv.z, acc[i][j][3] + bsv.w);
        *(uint2*)&ko[(((size_t)(b * 8 + hh)) * 1024 + s) * 64 + dd] = st;
      }
    } else {
      const int n2 = gn - 2560, hh = n2 >> 6, dd0 = n2 & 63;
#pragma unroll
      for (int i = 0; i < 8; ++i) {
        const int m = m0 + i * 16 + ln;
        const int b = m >> 10, s = m & 1023;
        const size_t vb = ((size_t)(b * 8 + hh) * 64 + dd0) * 1024 + s;
        vo[vb]        = f2bf(acc[i][j][0] + bsv.x);
        vo[vb + 1024] = f2bf(acc[i][j][1] + bsv.y);
        vo[vb + 2048] = f2bf(acc[i][j][2] + bsv.z);
        vo[vb + 3072] = f2bf(acc[i][j][3] + bsv.w);
      }
    }
  }
}

// =================== O projection: 256x128 tile, BK=64, 8 waves ===================
// (round-3 verified code)
__global__ __launch_bounds__(512, 2) void gemm_o(
    const u16* __restrict__ A, const u16* __restrict__ BT,
    const float* __restrict__ bias, u16* __restrict__ o0,
    const int* __restrict__ flag) {
  __shared__ __align__(16) u16 lds[49152];
  const int tid = threadIdx.x;
  const int wave = tid >> 6, lane = tid & 63;
  const int ln = lane & 15, quad = lane >> 4;
  const int sw8 = 8 * (quad ^ ((ln >> 1) & 3));
  const int wm = (wave >> 2) * 128, wn = (wave & 3) * 32;
  const int m0 = blockIdx.y * 256, n0 = blockIdx.x * 128;
  const int fl = *flag;

  u16* const A0b = lds;
  u16* const A1b = lds + 16384;
  u16* const B0b = lds + 32768;
  u16* const B1b = lds + 40960;

  const int srow = wave * 16 + (lane >> 2);
  const int skq = 8 * ((lane & 3) ^ ((lane >> 3) & 3));
  const u16* const sa = A + (size_t)(m0 + srow) * 2048 + skq;
  const u16* const sb = BT + (size_t)(n0 + srow) * 2048 + skq;
  const int dc8 = (wave * 64 + lane) * 8;

  auto stageA = [&](u16* dbase, int H, int kt) {
    const u16* s = sa + (size_t)H * 262144 + kt;
    u16* d = dbase + H * 4096 + dc8;
    gl_lds16(s, d);
    gl_lds16(s + 32, d + 8192);
  };
  auto stageB = [&](u16* dbase, int kt) {
    const u16* s = sb + kt;
    gl_lds16(s, dbase + dc8);
    gl_lds16(s + 32, dbase + dc8 + 4096);
  };

  f32x4 acc[8][2];
#pragma unroll
  for (int i = 0; i < 8; ++i)
#pragma unroll
    for (int j = 0; j < 2; ++j) acc[i][j] = {0.f, 0.f, 0.f, 0.f};

  bf16x8 aL[8], aH[8], b0f[2], b1f[2];
  auto rdAh = [&](bf16x8* dst, const u16* buf, int ibase) {
#pragma unroll
    for (int ii = 0; ii < 4; ++ii) {
      const int ro = (wm + (ibase + ii) * 16 + ln) * 32 + sw8;
      dst[ii * 2 + 0] = *(const bf16x8*)&buf[ro];
      dst[ii * 2 + 1] = *(const bf16x8*)&buf[ro + 8192];
    }
  };
  auto rdBj = [&](bf16x8* dst, const u16* buf, int j) {
    const int ro = (wn + j * 16 + ln) * 32 + sw8;
    dst[0] = *(const bf16x8*)&buf[ro];
    dst[1] = *(const bf16x8*)&buf[ro + 4096];
  };
  auto mma8 = [&](const bf16x8* a4, const bf16x8* bj, int ibase, int j) {
#pragma unroll
    for (int ii = 0; ii < 4; ++ii)
#pragma unroll
      for (int kh = 0; kh < 2; ++kh)
        acc[ibase + ii][j] = __builtin_amdgcn_mfma_f32_16x16x32_bf16(
            bj[kh], a4[ii * 2 + kh], acc[ibase + ii][j], 0, 0, 0);
  };

  stageA(A0b, 0, 0); stageA(A0b, 1, 0);
  stageB(B0b, 0);
  stageA(A1b, 0, 64); stageA(A1b, 1, 64);
  __asm__ volatile("s_waitcnt vmcnt(4)" ::: "memory");
  S_BAR();

#pragma unroll 1
  for (int it = 0; it < 16; ++it) {
    const int kk = it * 128;
#pragma unroll
    for (int h = 0; h < 2; ++h) {
      u16* const Ab = h ? A1b : A0b;
      u16* const Bb = h ? B1b : B0b;
      u16* const Bo = h ? B0b : B1b;
      const int kB = (kk + 64 + h * 64) & 2047;
      const int kA = (kk + 128 + h * 64) & 2047;
      rdAh(aL, Ab, 0); rdBj(b0f, Bb, 0);
      stageB(Bo, kB);
      S_BAR(); LGKM0();
      __builtin_amdgcn_s_setprio(1); mma8(aL, b0f, 0, 0); __builtin_amdgcn_s_setprio(0);
      S_BAR();
      rdAh(aH, Ab, 4); rdBj(b1f, Bb, 1);
      S_BAR(); LGKM0();
      __builtin_amdgcn_s_setprio(1); mma8(aH, b0f, 4, 0); __builtin_amdgcn_s_setprio(0);
      S_BAR();
      stageA(Ab, 0, kA);
      S_BAR();
      __builtin_amdgcn_s_setprio(1); mma8(aH, b1f, 4, 1); __builtin_amdgcn_s_setprio(0);
      S_BAR();
      stageA(Ab, 1, kA);
      S_BAR();
      __builtin_amdgcn_s_setprio(1); mma8(aL, b1f, 0, 1); __builtin_amdgcn_s_setprio(0);
      VMC(4);
      S_BAR();
    }
  }

#pragma unroll
  for (int j = 0; j < 2; ++j) {
    const int nbase = n0 + wn + j * 16 + quad * 4;
    const float4 bsv = *(const float4*)&bias[nbase];
#pragma unroll
    for (int i = 0; i < 8; ++i) {
      const int m = m0 + wm + i * 16 + ln;
      float v0 = acc[i][j][0] + bsv.x, v1 = acc[i][j][1] + bsv.y;
      float v2 = acc[i][j][2] + bsv.z, v3 = acc[i][j][3] + bsv.w;
      if (fl) {
        float4 st = {v0, v1, v2, v3};
        *(float4*)&((float*)o0)[(size_t)m * 2048 + nbase] = st;
      } else {
        uint2 st; st.x = pack2bf(v0, v1); st.y = pack2bf(v2, v3);
        *(uint2*)&o0[(size_t)m * 2048 + nbase] = st;
      }
    }
  }
}

// =============== flash attention: 32x32 MFMA, in-register P, 64 q-rows/wave ===============
// R3's proven double-buffer sync schedule kept VERBATIM (2 barriers/iter, counted VMC).
// New: 512 thr (8 waves), each wave serves TWO 32-q column blocks (A at q0, B at q0+32)
// -> every K/V LDS fragment read feeds 2 MFMA (LDS-port load per FLOP halved).
// Grid (2,128) = 256 blocks = 1/CU. Staging: 1 chunk/thread/tile,
// mapping r=(tid>>2)&63, koff=(tid>>8)*32, quad=(tid&3)^((r>>1)&3) == R3's chunk content.
__global__ __launch_bounds__(512, 2) void attn_kernel(
    const u16* __restrict__ q_ws, const u16* __restrict__ k_ws,
    const u16* __restrict__ vt_ws, u16* __restrict__ ctx) {
  __shared__ __align__(16) u16 lds[16384];
  const int tid = threadIdx.x;
  const int wave = tid >> 6, lane = tid & 63;
  const int l31 = lane & 31, hi = lane >> 5;
  const int sw = (l31 >> 1) & 3;
  const int qt = blockIdx.x, bh = blockIdx.y;
  const int b = bh >> 5, h = bh & 31, kvh = h >> 2;
  const int q0 = qt * 512 + wave * 64;
  const u16* const kptr = k_ws + (size_t)(b * 8 + kvh) * 65536;
  const u16* const vptr = vt_ws + (size_t)(b * 8 + kvh) * 65536;

  // Q B-frags for both column blocks (QSCALE pre-applied)
  bf16x8 qfA[4], qfB[4];
  {
    const size_t qa = (size_t)bh * 65536 + (size_t)(q0 + l31) * 64 + hi * 8;
    const size_t qb = qa + (size_t)32 * 64;
#pragma unroll
    for (int ck = 0; ck < 4; ++ck) {
      qfA[ck] = *(const bf16x8*)&q_ws[qa + ck * 16];
      qfB[ck] = *(const bf16x8*)&q_ws[qb + ck * 16];
    }
  }

  // staging: thread -> chunk tid (0..511); content row r, k/s-offset koff, swizzled quad
  const int r = (tid >> 2) & 63;
  const int sq8 = 8 * ((tid & 3) ^ ((r >> 1) & 3));
  const int koff = (tid >> 8) * 32;
  const u16* const ks = kptr + r * 64 + koff + sq8;
  const u16* const vs = vptr + r * 1024 + koff + sq8;
  u16* const kd = &lds[tid * 8];
  u16* const vd = &lds[8192 + tid * 8];

  auto stageK = [&](int buf, int tile) { gl_lds16(ks + tile * 4096, kd + buf * 4096); };
  auto stageV = [&](int buf, int tile) { gl_lds16(vs + tile * 64, vd + buf * 4096); };

  f32x16 oA0, oA1, oB0, oB1;
#pragma unroll
  for (int rr = 0; rr < 16; ++rr) { oA0[rr] = 0.f; oA1[rr] = 0.f; oB0[rr] = 0.f; oB1[rr] = 0.f; }
  float lsA = 0.f, lsB = 0.f;

  // QK^T for one 32-key half, both column blocks: each kf read feeds 2 MFMA
  auto qk2 = [&](int kh, int buf, f32x16& sA, f32x16& sB) {
#pragma unroll
    for (int rr = 0; rr < 16; ++rr) { sA[rr] = 0.f; sB[rr] = 0.f; }
#pragma unroll
    for (int ck = 0; ck < 4; ++ck) {
      const int dq = (((ck & 1) << 1) | hi) ^ sw;
      bf16x8 kf = *(const bf16x8*)&lds[buf * 4096 + kh * 1024 + (ck >> 1) * 2048 +
                                       l31 * 32 + dq * 8];
      sA = __builtin_amdgcn_mfma_f32_32x32x16_bf16(kf, qfA[ck], sA, 0, 0, 0);
      sB = __builtin_amdgcn_mfma_f32_32x32x16_bf16(kf, qfB[ck], sB, 0, 0, 0);
    }
  };

  auto softmax = [&](const f32x16& s, uint32_t* w, float& lsum) {
    float p[16];
#pragma unroll
    for (int rr = 0; rr < 16; ++rr) p[rr] = EXP2(s[rr]);
    float t0 = (p[0] + p[1]) + (p[2] + p[3]);
    float t1 = (p[4] + p[5]) + (p[6] + p[7]);
    float t2 = (p[8] + p[9]) + (p[10] + p[11]);
    float t3 = (p[12] + p[13]) + (p[14] + p[15]);
    lsum += (t0 + t1) + (t2 + t3);
#pragma unroll
    for (int a = 0; a < 4; ++a) {
      w[a * 2 + 0] = cvt_pk_bf16(p[4 * a + 0], p[4 * a + 1]);
      w[a * 2 + 1] = cvt_pk_bf16(p[4 * a + 2], p[4 * a + 3]);
    }
  };

  auto mkfrag = [&](uint32_t* w, int mm) -> bf16x8 {
    uint32_t x0 = w[4 * mm + 0], y0 = w[4 * mm + 2];
    uint32_t x1 = w[4 * mm + 1], y1 = w[4 * mm + 3];
    pl32_swap(x0, y0);
    pl32_swap(x1, y1);
    union { uint32_t u[4]; bf16x8 v; } pu;
    pu.u[0] = x0; pu.u[1] = x1; pu.u[2] = y0; pu.u[3] = y1;
    return pu.v;
  };

  // PV for one s16-chunk, both column blocks: each vf read feeds 2 MFMA
  auto pv2 = [&](uint32_t* wA, uint32_t* wB, int mm, int kh, int buf) {
    bf16x8 pA = mkfrag(wA, mm);
    bf16x8 pB = mkfrag(wB, mm);
    const int m = kh * 2 + mm;
    const int sq = ((((m & 1) << 1) | hi) ^ sw);
    const int vbase = 8192 + buf * 4096 + (m >> 1) * 2048 + l31 * 32 + sq * 8;
    bf16x8 vf0 = *(const bf16x8*)&lds[vbase];
    bf16x8 vf1 = *(const bf16x8*)&lds[vbase + 1024];
    oA0 = __builtin_amdgcn_mfma_f32_32x32x16_bf16(pA, vf0, oA0, 0, 0, 0);
    oA1 = __builtin_amdgcn_mfma_f32_32x32x16_bf16(pA, vf1, oA1, 0, 0, 0);
    oB0 = __builtin_amdgcn_mfma_f32_32x32x16_bf16(pB, vf0, oB0, 0, 0, 0);
    oB1 = __builtin_amdgcn_mfma_f32_32x32x16_bf16(pB, vf1, oB1, 0, 0, 0);
  };

  // prologue: tiles 0,1 -> bufs 0,1 (2 loads each); retire tile 0, keep tile 1 in flight
  stageK(0, 0); stageV(0, 0);
  stageK(1, 1); stageV(1, 1);
  VMC(2);
  S_BAR();

#pragma unroll 1
  for (int it = 0; it < 16; ++it) {
    const int c = it & 1;
    f32x16 sA, sB;
    qk2(0, c, sA, sB);
    uint32_t wA0[8], wB0[8];
    softmax(sA, wA0, lsA); softmax(sB, wB0, lsB);
    pv2(wA0, wB0, 0, 0, c); pv2(wA0, wB0, 1, 0, c);
    qk2(1, c, sA, sB);
    uint32_t wA1[8], wB1[8];
    softmax(sA, wA1, lsA); softmax(sB, wB1, lsB);
    pv2(wA1, wB1, 0, 1, c); pv2(wA1, wB1, 1, 1, c);
    if (it < 15) S_BAR();  // all waves done reading buf c
    if (it < 14) {
      stageK(c, it + 2); stageV(c, it + 2);
      VMC(2);              // retire tile it+1 (next iter's buf), keep it+2 in flight
      S_BAR();
    } else if (it == 14) {
      VMC(0);              // retire tile 15
      S_BAR();
    }
  }

  // epilogue: row-sum completion + normalize + store (both column blocks)
  float ltA = lsA + __shfl_xor(lsA, 32);
  float ltB = lsB + __shfl_xor(lsB, 32);
  const float invA = 1.0f / ltA;
  const float invB = 1.0f / ltB;
  const int ha = hi << 4;  // bpermute byte addr: 4*qr + 16*hi
  const size_t cb = (size_t)(b * 1024) * 2048 + (size_t)h * 64;
#pragma unroll
  for (int rr = 0; rr < 16; ++rr) {
    const int qr = (rr & 3) + 8 * (rr >> 2);
    float iqA = __uint_as_float(
        (uint32_t)__builtin_amdgcn_ds_bpermute(qr * 4 + ha, (int)__float_as_uint(invA)));
    float iqB = __uint_as_float(
        (uint32_t)__builtin_amdgcn_ds_bpermute(qr * 4 + ha, (int)__float_as_uint(invB)));
    const int qA = q0 + qr + 4 * hi;
    const size_t rowA = cb + (size_t)qA * 2048;
    const size_t rowB = rowA + (size_t)32 * 2048;
    ctx[rowA + l31]      = f2bf(oA0[rr] * iqA);
    ctx[rowA + 32 + l31] = f2bf(oA1[rr] * iqA);
    ctx[rowB + l31]      = f2bf(oB0[rr] * iqB);
    ctx[rowB + 32 + l31] = f2bf(oB1[rr] * iqB);
  }
}

extern "C" void kernel_launch(void* const* d_in, const int* in_sizes, int n_in,
                              void* d_out, int out_size, void* d_ws, size_t ws_size,
                              hipStream_t stream) {
  const void* x  = d_in[0];
  const void* Wq = d_in[1];
  const void* bq = d_in[2];
  const void* Wk = d_in[3];
  const void* bk = d_in[4];
  const void* Wv = d_in[5];
  const void* bv = d_in[6];
  const void* Wo = d_in[7];
  const void* bo = d_in[8];
  char* ws = (char*)d_ws;

  u16* WT    = (u16*)(ws + 0);          // [3072][2048] bf16 (WqT|WkT|WvT)
  u16* WoT   = (u16*)(ws + 12582912);   // [2048][2048]
  u16* q_ws  = (u16*)(ws + 20971520);   // [4,32,1024,64]
  u16* k_ws  = (u16*)(ws + 37748736);   // [4,8,1024,64]
  u16* vt_ws = (u16*)(ws + 41943040);   // [4,8,64,1024]
  u16* c_ws  = (u16*)(ws + 46137344);   // [4096][2048]
  u16* xb    = (u16*)(ws + 62914560);   // [4096][2048] bf16 x
  float* biasf = (float*)(ws + 79691776); // 5120 fp32 packed biases
  int* flag  = (int*)(ws + 79712256);

  detect_dtype<<<1, 256, 0, stream>>>((const u16*)x, flag);
  prep<<<4628, 256, 0, stream>>>(Wq, Wk, Wv, Wo, x, bq, bk, bv, bo,
                                 WT, WoT, xb, biasf, flag);

  gemm_qkv<<<dim3(8, 32), 512, 0, stream>>>(xb, WT, biasf, q_ws, k_ws, vt_ws);
  attn_kernel<<<dim3(2, 128), 512, 0, stream>>>(q_ws, k_ws, vt_ws, c_ws);
  gemm_o<<<dim3(16, 16), 512, 0, stream>>>(c_ws, WoT, biasf + 3072, (u16*)d_out, flag);
}